// Round 8
// baseline (509.266 us; speedup 1.0000x reference)
//
#include <hip/hip_runtime.h>
#include <cstdint>
#include <cstddef>

#define NB 16384
#define NA 8
#define NE 512
#define NK 1024   // 2E
#define NN 4096   // A*E

typedef __bf16 bf16x8 __attribute__((ext_vector_type(8)));
typedef float  f32x4  __attribute__((ext_vector_type(4)));
typedef uint16_t u16x8 __attribute__((ext_vector_type(8)));

__device__ __forceinline__ uint16_t cvt_bf16(float f) {
    uint32_t u = __builtin_bit_cast(uint32_t, f);
    u += 0x7fffu + ((u >> 16) & 1u);
    return (uint16_t)(u >> 16);
}

// legacy BK=32 chunk swizzle (k_prep only)
__device__ __forceinline__ int swz(int row) { return (row ^ (row >> 2)) & 3; }

__device__ __forceinline__ void gl_lds16(const void* g, void* l) {
    __builtin_amdgcn_global_load_lds(
        (__attribute__((address_space(1))) void*)(void*)g,
        (__attribute__((address_space(3))) void*)l, 16, 0, 0);
}

// f32 [nmat][R][C] -> bf16 [nmat][C][R]
__global__ __launch_bounds__(256) void k_tcvt(const float* __restrict__ in,
                                              uint16_t* __restrict__ out,
                                              int R, int C) {
    __shared__ float tile[32][33];
    int mat = blockIdx.z;
    int c0 = blockIdx.x * 32, r0 = blockIdx.y * 32;
    int tx = threadIdx.x & 31, ty = threadIdx.x >> 5;
    const float* src = in + (size_t)mat * R * C;
    uint16_t* dst = out + (size_t)mat * R * C;
#pragma unroll
    for (int yy = 0; yy < 4; ++yy) {
        int r = ty + yy * 8;
        tile[r][tx] = src[(size_t)(r0 + r) * C + c0 + tx];
    }
    __syncthreads();
#pragma unroll
    for (int yy = 0; yy < 4; ++yy) {
        int c = ty + yy * 8;
        dst[(size_t)(c0 + c) * R + r0 + tx] = cvt_bf16(tile[tx][c]);
    }
}

// f32 -> bf16 flat, 4 elems/thread
__global__ __launch_bounds__(256) void k_cvt4(const float* __restrict__ in,
                                              uint16_t* __restrict__ out, int n4) {
    int i = blockIdx.x * 256 + threadIdx.x;
    if (i >= n4) return;
    float4 v = ((const float4*)in)[i];
    ushort4 o;
    o.x = cvt_bf16(v.x); o.y = cvt_bf16(v.y); o.z = cvt_bf16(v.z); o.w = cvt_bf16(v.w);
    ((ushort4*)out)[i] = o;
}

// bvec[a*E+j] += partial over 32 i's; 128 blocks, atomics (bvec pre-zeroed)
__global__ __launch_bounds__(256) void k_bvec(const float* __restrict__ lb,
                                              const float* __restrict__ fwd,
                                              float* __restrict__ bvec) {
    int a = blockIdx.x >> 4, i0 = (blockIdx.x & 15) * 32;
    int t = threadIdx.x;
    float s0 = 0.f, s1 = 0.f;
#pragma unroll 4
    for (int i = 0; i < 32; ++i) {
        float w = lb[i0 + i];
        const float* f = fwd + ((size_t)a * NE + i0 + i) * NE;
        s0 = fmaf(w, f[t], s0);
        s1 = fmaf(w, f[t + 256], s1);
    }
    atomicAdd(&bvec[a * NE + t], s0);
    atomicAdd(&bvec[a * NE + t + 256], s1);
}

// TM[m=k'(1024)][n=(a,j)(4096)] = sum_i lwT[m][i]*fwdT[n][i]; store TMT[n][m] bf16
__global__ __launch_bounds__(256) void k_prep(const uint16_t* __restrict__ lwT,
                                              const uint16_t* __restrict__ fwdT,
                                              uint16_t* __restrict__ TMT) {
    __shared__ alignas(16) uint16_t lA[128 * 32];
    __shared__ alignas(16) uint16_t lB[128 * 32];
    int bz = blockIdx.x;
    int nt = bz & 31, mt = bz >> 5;
    int m0 = mt * 128, n0 = nt * 128;
    int t = threadIdx.x, lane = t & 63;
    int w = t >> 6, wm = w >> 1, wn = w & 1;
    int lr = lane & 15, lc = lane >> 4;
    int sl = swz(lr);
    f32x4 acc[4][4] = {};
    for (int k0 = 0; k0 < NE; k0 += 32) {
        __syncthreads();
#pragma unroll
        for (int p = 0; p < 2; ++p) {
            int idx = p * 256 + t;
            int row = idx >> 2, c16 = (idx & 3) ^ swz(row);
            gl_lds16(lwT + (size_t)(m0 + row) * NE + k0 + c16 * 8, lA + idx * 8);
            gl_lds16(fwdT + (size_t)(n0 + row) * NE + k0 + c16 * 8, lB + idx * 8);
        }
        __syncthreads();
        bf16x8 af[4], bfr[4];
#pragma unroll
        for (int i = 0; i < 4; ++i)
            af[i] = *(const bf16x8*)&lA[(wm * 64 + i * 16 + lr) * 32 + ((lc ^ sl) << 3)];
#pragma unroll
        for (int j = 0; j < 4; ++j)
            bfr[j] = *(const bf16x8*)&lB[(wn * 64 + j * 16 + lr) * 32 + ((lc ^ sl) << 3)];
#pragma unroll
        for (int i = 0; i < 4; ++i)
#pragma unroll
            for (int j = 0; j < 4; ++j)
                acc[i][j] = __builtin_amdgcn_mfma_f32_16x16x32_bf16(af[i], bfr[j], acc[i][j], 0, 0, 0);
    }
#pragma unroll
    for (int i = 0; i < 4; ++i) {
        int mb = m0 + wm * 64 + i * 16 + lc * 4;
#pragma unroll
        for (int j = 0; j < 4; ++j) {
            int n = n0 + wn * 64 + j * 16 + lr;
            ushort4 v;
            v.x = cvt_bf16(acc[i][j][0]);
            v.y = cvt_bf16(acc[i][j][1]);
            v.z = cvt_bf16(acc[i][j][2]);
            v.w = cvt_bf16(acc[i][j][3]);
            *(ushort4*)&TMT[(size_t)n * NK + mb] = v;
        }
    }
}

// attr[b,a,j] = img[b]@TM_a[0:512] + edge[b,a]@TM_a[512:1024] + bvec_a[j]
// m97 structure: 512 thr / 8 waves, 128x256 tile, BK=64, SINGLE buffer,
// 2 barriers/step, chunk^(row&7) swizzle (0-conflict @BK=64, R3 PMC),
// a=XCD map, fused f32 edge with T14 issue-early/write-late.
template<bool WB>
__global__ __launch_bounds__(512) void k_mm5(const uint16_t* __restrict__ imgb,
                                             const float* __restrict__ edge,
                                             const uint16_t* __restrict__ TMT,
                                             const float* __restrict__ bvec,
                                             float* __restrict__ attr,
                                             uint16_t* __restrict__ attrb) {
    __shared__ alignas(16) uint16_t lA[128 * 64];   // 16 KB
    __shared__ alignas(16) uint16_t lB[256 * 64];   // 32 KB
    int o = blockIdx.x;             // 2048 = 8 xcd * (2 jt * 128 mt)
    int a = o & 7, idx = o >> 3;
    int jt = idx & 1, mt = idx >> 1;
    int m0 = mt * 128, jb = jt * 256;
    int t = threadIdx.x, lane = t & 63;
    int w = t >> 6, wm = w >> 2, wn = w & 3;
    int lr = lane & 15, lc = lane >> 4;   // lc in [0,4)
    // gl_lds source maps (inverse swizzle): unit u -> row=u>>3, chunk c=(u&7)^(row&7)
    int srA[2], scA[2];
#pragma unroll
    for (int p = 0; p < 2; ++p) {
        int u = t + p * 512;
        srA[p] = u >> 3;
        scA[p] = ((u & 7) ^ (srA[p] & 7)) << 3;
    }
    int srB[4], scB[4];
#pragma unroll
    for (int p = 0; p < 4; ++p) {
        int u = t + p * 512;
        srB[p] = u >> 3;
        scB[p] = ((u & 7) ^ (srB[p] & 7)) << 3;
    }
    // edge reg-stage: thread owns 2 natural (row, 8-elem chunk) slots
    int erw[2], ecc[2], eps[2];
#pragma unroll
    for (int p = 0; p < 2; ++p) {
        int u = t + p * 512;
        erw[p] = u >> 3; ecc[p] = u & 7;
        eps[p] = ((erw[p] << 3) + (ecc[p] ^ (erw[p] & 7))) << 3;
    }
    // fragment rows + swizzle keys
    int arow[4], brow[4];
#pragma unroll
    for (int i = 0; i < 4; ++i) {
        arow[i] = wm * 64 + i * 16 + lr;
        brow[i] = wn * 64 + i * 16 + lr;
    }
    float4 ereg[2][2];
    auto load_edge = [&](int s) {   // s in [8,16)
        int kk = (s - 8) * 64;
#pragma unroll
        for (int p = 0; p < 2; ++p) {
            const float* sp = edge + ((size_t)(m0 + erw[p]) * NA + a) * NE + kk + ecc[p] * 8;
            ereg[p][0] = ((const float4*)sp)[0];
            ereg[p][1] = ((const float4*)sp)[1];
        }
    };
    f32x4 acc[4][4] = {};
    for (int s = 0; s < 16; ++s) {
        __syncthreads();            // prior compute done reading LDS
        if (s < 8) {
#pragma unroll
            for (int p = 0; p < 2; ++p)
                gl_lds16(imgb + (size_t)(m0 + srA[p]) * NE + s * 64 + scA[p],
                         &lA[(t + p * 512) * 8]);
        } else {
#pragma unroll
            for (int p = 0; p < 2; ++p) {
                u16x8 ov = {cvt_bf16(ereg[p][0].x), cvt_bf16(ereg[p][0].y),
                            cvt_bf16(ereg[p][0].z), cvt_bf16(ereg[p][0].w),
                            cvt_bf16(ereg[p][1].x), cvt_bf16(ereg[p][1].y),
                            cvt_bf16(ereg[p][1].z), cvt_bf16(ereg[p][1].w)};
                *(u16x8*)&lA[eps[p]] = ov;
            }
        }
#pragma unroll
        for (int p = 0; p < 4; ++p)
            gl_lds16(TMT + (size_t)(a * NE + jb + srB[p]) * NK + s * 64 + scB[p],
                     &lB[(t + p * 512) * 8]);
        __syncthreads();            // staged data visible (drains vmcnt)
        if (s >= 7 && s < 15) load_edge(s + 1);  // issue early; lands under MFMA
#pragma unroll
        for (int h = 0; h < 2; ++h) {
            bf16x8 af[4], bfr[4];
#pragma unroll
            for (int i = 0; i < 4; ++i)
                af[i] = *(const bf16x8*)&lA[(arow[i] << 6) + ((((h << 2) + lc) ^ (arow[i] & 7)) << 3)];
#pragma unroll
            for (int j = 0; j < 4; ++j)
                bfr[j] = *(const bf16x8*)&lB[(brow[j] << 6) + ((((h << 2) + lc) ^ (brow[j] & 7)) << 3)];
#pragma unroll
            for (int i = 0; i < 4; ++i)
#pragma unroll
                for (int j = 0; j < 4; ++j)
                    acc[i][j] = __builtin_amdgcn_mfma_f32_16x16x32_bf16(af[i], bfr[j], acc[i][j], 0, 0, 0);
        }
    }
#pragma unroll
    for (int j = 0; j < 4; ++j) {
        float bv = bvec[a * NE + jb + wn * 64 + j * 16 + lr];
#pragma unroll
        for (int i = 0; i < 4; ++i)
#pragma unroll
            for (int r = 0; r < 4; ++r)
                acc[i][j][r] += bv;
    }
#pragma unroll
    for (int i = 0; i < 4; ++i) {
#pragma unroll
        for (int r = 0; r < 4; ++r) {
            int bm = m0 + wm * 64 + i * 16 + lc * 4 + r;
            float* orow = attr + ((size_t)bm * NA + a) * NE + jb;
#pragma unroll
            for (int j = 0; j < 4; ++j)
                orow[wn * 64 + j * 16 + lr] = acc[i][j][r];
            if (WB) {
                uint16_t* brw = attrb + ((size_t)bm * NA + a) * NE + jb;
#pragma unroll
                for (int j = 0; j < 4; ++j)
                    brw[wn * 64 + j * 16 + lr] = cvt_bf16(acc[i][j][r]);
            }
        }
    }
}

// ind[b,j] += sum_{a in pair} sw[a]*relu(attrb[b,a,:]@bwd_a[:,j])
// Same m97 structure: 512 thr, 128x256 tile, BK=64 single buffer,
// (jt,ah)=XCD, a-split-4 atomics (ind pre-zeroed).
template<bool AB>
__global__ __launch_bounds__(512) void k_ind5(const float* __restrict__ attrf,
                                              const uint16_t* __restrict__ attrb,
                                              const uint16_t* __restrict__ bwdT,
                                              const float* __restrict__ sw,
                                              float* __restrict__ ind) {
    __shared__ alignas(16) uint16_t lA[128 * 64];   // 16 KB
    __shared__ alignas(16) uint16_t lB[256 * 64];   // 32 KB
    int o = blockIdx.x;             // 1024 = 8 xcd * 128 mt
    int g = o & 7, mt = o >> 3;
    int jt = g & 1, ah = g >> 1;    // jt in [0,2), ah in [0,4)
    int m0 = mt * 128, jb = jt * 256, a0 = ah * 2;
    int t = threadIdx.x, lane = t & 63;
    int w = t >> 6, wm = w >> 2, wn = w & 3;
    int lr = lane & 15, lc = lane >> 4;
    int srA[2], scA[2];
#pragma unroll
    for (int p = 0; p < 2; ++p) {
        int u = t + p * 512;
        srA[p] = u >> 3;
        scA[p] = ((u & 7) ^ (srA[p] & 7)) << 3;
    }
    int srB[4], scB[4];
#pragma unroll
    for (int p = 0; p < 4; ++p) {
        int u = t + p * 512;
        srB[p] = u >> 3;
        scB[p] = ((u & 7) ^ (srB[p] & 7)) << 3;
    }
    int erw[2], ecc[2], eps[2];
#pragma unroll
    for (int p = 0; p < 2; ++p) {
        int u = t + p * 512;
        erw[p] = u >> 3; ecc[p] = u & 7;
        eps[p] = ((erw[p] << 3) + (ecc[p] ^ (erw[p] & 7))) << 3;
    }
    int arow[4], brow[4];
#pragma unroll
    for (int i = 0; i < 4; ++i) {
        arow[i] = wm * 64 + i * 16 + lr;
        brow[i] = wn * 64 + i * 16 + lr;
    }
    float wav[2] = {sw[a0], sw[a0 + 1]};
    f32x4 res[4][4] = {};
    f32x4 acc[4][4] = {};
    for (int s = 0; s < 16; ++s) {
        int aa = a0 + (s >> 3), kk = (s & 7) * 64;
        __syncthreads();
        if (AB) {
#pragma unroll
            for (int p = 0; p < 2; ++p)
                gl_lds16(attrb + ((size_t)(m0 + srA[p]) * NA + aa) * NE + kk + scA[p],
                         &lA[(t + p * 512) * 8]);
        } else {
#pragma unroll
            for (int p = 0; p < 2; ++p) {
                const float* sp = attrf + ((size_t)(m0 + erw[p]) * NA + aa) * NE + kk + ecc[p] * 8;
                float4 v0 = ((const float4*)sp)[0];
                float4 v1 = ((const float4*)sp)[1];
                u16x8 ov = {cvt_bf16(v0.x), cvt_bf16(v0.y), cvt_bf16(v0.z), cvt_bf16(v0.w),
                            cvt_bf16(v1.x), cvt_bf16(v1.y), cvt_bf16(v1.z), cvt_bf16(v1.w)};
                *(u16x8*)&lA[eps[p]] = ov;
            }
        }
#pragma unroll
        for (int p = 0; p < 4; ++p)
            gl_lds16(bwdT + (size_t)(aa * NE + jb + srB[p]) * NE + kk + scB[p],
                     &lB[(t + p * 512) * 8]);
        __syncthreads();
#pragma unroll
        for (int h = 0; h < 2; ++h) {
            bf16x8 af[4], bfr[4];
#pragma unroll
            for (int i = 0; i < 4; ++i)
                af[i] = *(const bf16x8*)&lA[(arow[i] << 6) + ((((h << 2) + lc) ^ (arow[i] & 7)) << 3)];
#pragma unroll
            for (int j = 0; j < 4; ++j)
                bfr[j] = *(const bf16x8*)&lB[(brow[j] << 6) + ((((h << 2) + lc) ^ (brow[j] & 7)) << 3)];
#pragma unroll
            for (int i = 0; i < 4; ++i)
#pragma unroll
                for (int j = 0; j < 4; ++j)
                    acc[i][j] = __builtin_amdgcn_mfma_f32_16x16x32_bf16(af[i], bfr[j], acc[i][j], 0, 0, 0);
        }
        if ((s & 7) == 7) {
            float wa = wav[s >> 3];
#pragma unroll
            for (int i = 0; i < 4; ++i)
#pragma unroll
                for (int j = 0; j < 4; ++j) {
#pragma unroll
                    for (int r = 0; r < 4; ++r)
                        res[i][j][r] += wa * fmaxf(acc[i][j][r], 0.f);
                    acc[i][j] = (f32x4){0.f, 0.f, 0.f, 0.f};
                }
        }
    }
#pragma unroll
    for (int i = 0; i < 4; ++i) {
#pragma unroll
        for (int r = 0; r < 4; ++r) {
            int bm = m0 + wm * 64 + i * 16 + lc * 4 + r;
            float* orow = ind + (size_t)bm * NE + jb;
#pragma unroll
            for (int j = 0; j < 4; ++j)
                atomicAdd(&orow[wn * 64 + j * 16 + lr], res[i][j][r]);
        }
    }
}

extern "C" void kernel_launch(void* const* d_in, const int* in_sizes, int n_in,
                              void* d_out, int out_size, void* d_ws, size_t ws_size,
                              hipStream_t stream) {
    (void)in_sizes; (void)n_in; (void)out_size;
    const float* img  = (const float*)d_in[0];
    const float* edge = (const float*)d_in[1];
    const float* lw   = (const float*)d_in[2];
    const float* lb   = (const float*)d_in[3];
    const float* fwd  = (const float*)d_in[4];
    const float* bwd  = (const float*)d_in[5];
    const float* sw   = (const float*)d_in[6];
    float* attr = (float*)d_out;
    float* ind  = attr + (size_t)NB * NA * NE;

    char* ws = (char*)d_ws;
    size_t off = 0;
    auto alloc = [&](size_t bytes) { void* p = ws + off; off += bytes; return p; };
    uint16_t* lwT  = (uint16_t*)alloc((size_t)NK * NE * 2);       // 1 MB
    uint16_t* fwdT = (uint16_t*)alloc((size_t)NA * NE * NE * 2);  // 4 MB
    uint16_t* bwdT = (uint16_t*)alloc((size_t)NA * NE * NE * 2);  // 4 MB
    uint16_t* TMT  = (uint16_t*)alloc((size_t)NN * NK * 2);       // 8 MB
    uint16_t* imgb = (uint16_t*)alloc((size_t)NB * NE * 2);       // 16 MB
    float*    bvec = (float*)alloc((size_t)NN * 4);               // 16 KB

    const size_t BIGB = (size_t)NB * NA * NE * 2;  // 128 MB
    bool has_attrb = ws_size >= off + BIGB;
    uint16_t* attrb = has_attrb ? (uint16_t*)alloc(BIGB) : (uint16_t*)0;

    hipMemsetAsync(bvec, 0, (size_t)NN * 4, stream);
    hipMemsetAsync(ind, 0, (size_t)NB * NE * 4, stream);
    k_tcvt<<<dim3(NK / 32, NE / 32, 1), 256, 0, stream>>>(lw, lwT, NE, NK);
    k_tcvt<<<dim3(NE / 32, NE / 32, NA), 256, 0, stream>>>(fwd, fwdT, NE, NE);
    k_tcvt<<<dim3(NE / 32, NE / 32, NA), 256, 0, stream>>>(bwd, bwdT, NE, NE);
    k_cvt4<<<NB * NE / 4 / 256, 256, 0, stream>>>(img, imgb, NB * NE / 4);
    k_bvec<<<128, 256, 0, stream>>>(lb, fwd, bvec);
    k_prep<<<(NK / 128) * (NN / 128), 256, 0, stream>>>(lwT, fwdT, TMT);

    int mm_grid = 8 * 2 * (NB / 128);        // 2048 blocks of 512 threads
    int ind_grid = 8 * (NB / 128);           // 1024 blocks of 512 threads

    if (has_attrb) {
        k_mm5<true><<<mm_grid, 512, 0, stream>>>(imgb, edge, TMT, bvec, attr, attrb);
        k_ind5<true><<<ind_grid, 512, 0, stream>>>(attr, attrb, bwdT, sw, ind);
    } else {
        k_mm5<false><<<mm_grid, 512, 0, stream>>>(imgb, edge, TMT, bvec, attr, attrb);
        k_ind5<false><<<ind_grid, 512, 0, stream>>>(attr, attrb, bwdT, sw, ind);
    }
}

// Round 9
// 500.339 us; speedup vs baseline: 1.0178x; 1.0178x over previous
//
#include <hip/hip_runtime.h>
#include <cstdint>
#include <cstddef>

#define NB 16384
#define NA 8
#define NE 512
#define NK 1024   // 2E
#define NN 4096   // A*E

typedef __bf16 bf16x8 __attribute__((ext_vector_type(8)));
typedef float  f32x4  __attribute__((ext_vector_type(4)));
typedef uint16_t u16x8 __attribute__((ext_vector_type(8)));

__device__ __forceinline__ uint16_t cvt_bf16(float f) {
    uint32_t u = __builtin_bit_cast(uint32_t, f);
    u += 0x7fffu + ((u >> 16) & 1u);
    return (uint16_t)(u >> 16);
}

// legacy BK=32 chunk swizzle (k_prep only)
__device__ __forceinline__ int swz(int row) { return (row ^ (row >> 2)) & 3; }

// conflict-free BK=32 tile position (16B units): row-pair interleave + 3-bit XOR
// proven 0-conflict in R5/R6/R7 PMC
__device__ __forceinline__ int cf_pos(int row, int c) {
    return ((row >> 1) << 3) + ((((row & 1) << 2) + c) ^ ((row >> 1) & 7));
}

__device__ __forceinline__ void gl_lds16(const void* g, void* l) {
    __builtin_amdgcn_global_load_lds(
        (__attribute__((address_space(1))) void*)(void*)g,
        (__attribute__((address_space(3))) void*)l, 16, 0, 0);
}

// ---- fused prep: lw/fwd/bwd transpose-cvt + img cvt + bvec, one launch ----
__device__ __forceinline__ void tcvt_tile(const float* __restrict__ src,
                                          uint16_t* __restrict__ dst,
                                          int R, int C, int c0, int r0, int t) {
    __shared__ float tile[32][33];
    int tx = t & 31, ty = t >> 5;
#pragma unroll
    for (int yy = 0; yy < 4; ++yy) {
        int r = ty + yy * 8;
        tile[r][tx] = src[(size_t)(r0 + r) * C + c0 + tx];
    }
    __syncthreads();
#pragma unroll
    for (int yy = 0; yy < 4; ++yy) {
        int c = ty + yy * 8;
        dst[(size_t)(c0 + c) * R + r0 + tx] = cvt_bf16(tile[tx][c]);
    }
}

__global__ __launch_bounds__(256) void k_pre(const float* __restrict__ lw,
                                             const float* __restrict__ fwd,
                                             const float* __restrict__ bwd,
                                             const float* __restrict__ img,
                                             const float* __restrict__ lb,
                                             uint16_t* __restrict__ lwT,
                                             uint16_t* __restrict__ fwdT,
                                             uint16_t* __restrict__ bwdT,
                                             uint16_t* __restrict__ imgb,
                                             float* __restrict__ bvec) {
    int b = blockIdx.x, t = threadIdx.x;
    if (b < 512) {                       // lw: [512][1024] -> lwT [1024][512]
        int bx = b & 31, by = b >> 5;
        tcvt_tile(lw, lwT, NE, NK, bx * 32, by * 32, t);
    } else if (b < 2560) {               // fwd: 8 mats [512][512] -> [j][i]
        int i = b - 512;
        int mat = i >> 8, bx = i & 15, by = (i >> 4) & 15;
        tcvt_tile(fwd + (size_t)mat * NE * NE, fwdT + (size_t)mat * NE * NE,
                  NE, NE, bx * 32, by * 32, t);
    } else if (b < 4608) {               // bwd
        int i = b - 2560;
        int mat = i >> 8, bx = i & 15, by = (i >> 4) & 15;
        tcvt_tile(bwd + (size_t)mat * NE * NE, bwdT + (size_t)mat * NE * NE,
                  NE, NE, bx * 32, by * 32, t);
    } else if (b < 12800) {              // img f32 -> bf16, 4/thread
        int i = (b - 4608) * 256 + t;
        float4 v = ((const float4*)img)[i];
        ushort4 o;
        o.x = cvt_bf16(v.x); o.y = cvt_bf16(v.y); o.z = cvt_bf16(v.z); o.w = cvt_bf16(v.w);
        ((ushort4*)imgb)[i] = o;
    } else {                             // bvec partials (bvec pre-zeroed)
        int i = b - 12800;
        int a = i >> 4, i0 = (i & 15) * 32;
        float s0 = 0.f, s1 = 0.f;
#pragma unroll 4
        for (int k = 0; k < 32; ++k) {
            float w = lb[i0 + k];
            const float* f = fwd + ((size_t)a * NE + i0 + k) * NE;
            s0 = fmaf(w, f[t], s0);
            s1 = fmaf(w, f[t + 256], s1);
        }
        atomicAdd(&bvec[a * NE + t], s0);
        atomicAdd(&bvec[a * NE + t + 256], s1);
    }
}

// TM[m=k'(1024)][n=(a,j)(4096)] = sum_i lwT[m][i]*fwdT[n][i]; store TMT[n][m] bf16
__global__ __launch_bounds__(256) void k_prep(const uint16_t* __restrict__ lwT,
                                              const uint16_t* __restrict__ fwdT,
                                              uint16_t* __restrict__ TMT) {
    __shared__ alignas(16) uint16_t lA[128 * 32];
    __shared__ alignas(16) uint16_t lB[128 * 32];
    int bz = blockIdx.x;
    int nt = bz & 31, mt = bz >> 5;
    int m0 = mt * 128, n0 = nt * 128;
    int t = threadIdx.x, lane = t & 63;
    int w = t >> 6, wm = w >> 1, wn = w & 1;
    int lr = lane & 15, lc = lane >> 4;
    int sl = swz(lr);
    f32x4 acc[4][4] = {};
    for (int k0 = 0; k0 < NE; k0 += 32) {
        __syncthreads();
#pragma unroll
        for (int p = 0; p < 2; ++p) {
            int idx = p * 256 + t;
            int row = idx >> 2, c16 = (idx & 3) ^ swz(row);
            gl_lds16(lwT + (size_t)(m0 + row) * NE + k0 + c16 * 8, lA + idx * 8);
            gl_lds16(fwdT + (size_t)(n0 + row) * NE + k0 + c16 * 8, lB + idx * 8);
        }
        __syncthreads();
        bf16x8 af[4], bfr[4];
#pragma unroll
        for (int i = 0; i < 4; ++i)
            af[i] = *(const bf16x8*)&lA[(wm * 64 + i * 16 + lr) * 32 + ((lc ^ sl) << 3)];
#pragma unroll
        for (int j = 0; j < 4; ++j)
            bfr[j] = *(const bf16x8*)&lB[(wn * 64 + j * 16 + lr) * 32 + ((lc ^ sl) << 3)];
#pragma unroll
        for (int i = 0; i < 4; ++i)
#pragma unroll
            for (int j = 0; j < 4; ++j)
                acc[i][j] = __builtin_amdgcn_mfma_f32_16x16x32_bf16(af[i], bfr[j], acc[i][j], 0, 0, 0);
    }
#pragma unroll
    for (int i = 0; i < 4; ++i) {
        int mb = m0 + wm * 64 + i * 16 + lc * 4;
#pragma unroll
        for (int j = 0; j < 4; ++j) {
            int n = n0 + wn * 64 + j * 16 + lr;
            ushort4 v;
            v.x = cvt_bf16(acc[i][j][0]);
            v.y = cvt_bf16(acc[i][j][1]);
            v.z = cvt_bf16(acc[i][j][2]);
            v.w = cvt_bf16(acc[i][j][3]);
            *(ushort4*)&TMT[(size_t)n * NK + mb] = v;
        }
    }
}

// attr[b,a,j] = img[b]@TM_a[0:512] + edge[b,a]@TM_a[512:1024] + bvec_a[j]
// R7 structure: 512 thr / 8 waves, 128x256 tile, BK=32 dbuf, cf_pos layout,
// a=XCD, fused edge f32 (T14 load-early / cvt+ds_write-late). No attrb.
__global__ __launch_bounds__(512) void k_mm4(const uint16_t* __restrict__ imgb,
                                             const float* __restrict__ edge,
                                             const uint16_t* __restrict__ TMT,
                                             const float* __restrict__ bvec,
                                             float* __restrict__ attr) {
    __shared__ alignas(16) uint16_t lA[2][128 * 32];   // 2 x 8 KB
    __shared__ alignas(16) uint16_t lB[2][256 * 32];   // 2 x 16 KB
    int o = blockIdx.x;             // 2048 = 8 xcd * (2 jt * 128 mt)
    int a = o & 7, idx = o >> 3;
    int jt = idx & 1, mt = idx >> 1;
    int m0 = mt * 128, jb = jt * 256;
    int t = threadIdx.x, lane = t & 63;
    int w = t >> 6, wm = w >> 2, wn = w & 3;
    int lr = lane & 15, lc = lane >> 4;
    // A stage map (1 unit/thread): inverse of cf_pos
    int rpA = t >> 3, qA = (t & 7) ^ (rpA & 7);
    int srA = (rpA << 1) | (qA >> 2), scA = (qA & 3) << 3;
    // B stage map (2 units/thread)
    int srB[2], scB[2];
#pragma unroll
    for (int p = 0; p < 2; ++p) {
        int u = t + p * 512;
        int rp = u >> 3, q = (u & 7) ^ (rp & 7);
        srB[p] = (rp << 1) | (q >> 2);
        scB[p] = (q & 3) << 3;
    }
    // edge f32 path: thread owns (row, chunk) natural, writes swizzled
    int er = t >> 2, ec = t & 3;
    int epos = cf_pos(er, ec) * 8;
    int aoff[4], boff[4];
#pragma unroll
    for (int i = 0; i < 4; ++i) {
        aoff[i] = cf_pos(wm * 64 + i * 16 + lr, lc) * 8;
        boff[i] = cf_pos(wn * 64 + i * 16 + lr, lc) * 8;
    }
    auto stage_img = [&](int buf, int s) {
        gl_lds16(imgb + (size_t)(m0 + srA) * NE + s * 32 + scA, &lA[buf][t * 8]);
    };
    auto stage_tmt = [&](int buf, int s) {
#pragma unroll
        for (int p = 0; p < 2; ++p)
            gl_lds16(TMT + (size_t)(a * NE + jb + srB[p]) * NK + s * 32 + scB[p],
                     &lB[buf][(t + p * 512) * 8]);
    };
    f32x4 acc[4][4] = {};
    stage_img(0, 0);
    stage_tmt(0, 0);
    for (int s = 0; s < 32; ++s) {
        int cur = s & 1, nb = cur ^ 1;
        __syncthreads();
        float4 e0, e1;
        bool eN = (s < 31) && (s + 1 >= 16);
        if (s < 31) {
            if (s + 1 < 16) {
                stage_img(nb, s + 1);
            } else {
                int kk = (s + 1 - 16) * 32;
                const float* sp = edge + ((size_t)(m0 + er) * NA + a) * NE + kk + ec * 8;
                e0 = ((const float4*)sp)[0];
                e1 = ((const float4*)sp)[1];
            }
            stage_tmt(nb, s + 1);
        }
        bf16x8 af[4], bfr[4];
#pragma unroll
        for (int i = 0; i < 4; ++i) af[i] = *(const bf16x8*)&lA[cur][aoff[i]];
#pragma unroll
        for (int j = 0; j < 4; ++j) bfr[j] = *(const bf16x8*)&lB[cur][boff[j]];
#pragma unroll
        for (int i = 0; i < 4; ++i)
#pragma unroll
            for (int j = 0; j < 4; ++j)
                acc[i][j] = __builtin_amdgcn_mfma_f32_16x16x32_bf16(af[i], bfr[j], acc[i][j], 0, 0, 0);
        if (eN) {
            u16x8 ov = {cvt_bf16(e0.x), cvt_bf16(e0.y), cvt_bf16(e0.z), cvt_bf16(e0.w),
                        cvt_bf16(e1.x), cvt_bf16(e1.y), cvt_bf16(e1.z), cvt_bf16(e1.w)};
            *(u16x8*)&lA[nb][epos] = ov;
        }
    }
#pragma unroll
    for (int j = 0; j < 4; ++j) {
        float bv = bvec[a * NE + jb + wn * 64 + j * 16 + lr];
#pragma unroll
        for (int i = 0; i < 4; ++i)
#pragma unroll
            for (int r = 0; r < 4; ++r)
                acc[i][j][r] += bv;
    }
#pragma unroll
    for (int i = 0; i < 4; ++i) {
#pragma unroll
        for (int r = 0; r < 4; ++r) {
            int bm = m0 + wm * 64 + i * 16 + lc * 4 + r;
            float* orow = attr + ((size_t)bm * NA + a) * NE + jb;
#pragma unroll
            for (int j = 0; j < 4; ++j)
                orow[wn * 64 + j * 16 + lr] = acc[i][j][r];
        }
    }
}

// ind[b,j] += sum_{a in half} sw[a]*relu(attr[b,a,:]@bwd_a[:,j])
// R7 structure: 256 thr, 128x128 tile, BK=32 dbuf, cf_pos, (jt,ah)=XCD,
// a-split-2 atomics. Reads attr f32 directly (reg-cvt stage).
__global__ __launch_bounds__(256) void k_ind4(const float* __restrict__ attrf,
                                              const uint16_t* __restrict__ bwdT,
                                              const float* __restrict__ sw,
                                              float* __restrict__ ind) {
    __shared__ alignas(16) uint16_t lA[2][128 * 32];
    __shared__ alignas(16) uint16_t lB[2][128 * 32];
    int o = blockIdx.x;            // 1024 = 8 xcd * 128 mt
    int xcd = o & 7, mt = o >> 3;
    int jt = xcd >> 1, ah = xcd & 1;
    int m0 = mt * 128, jb = jt * 128, a0 = ah * 4;
    int t = threadIdx.x, lane = t & 63;
    int w = t >> 6, wm = w >> 1, wn = w & 1;
    int lr = lane & 15, lc = lane >> 4;
    int srow[2], sc8[2];
#pragma unroll
    for (int p = 0; p < 2; ++p) {
        int u = p * 256 + t;
        int rp = u >> 3, q = (u & 7) ^ (rp & 7);
        srow[p] = (rp << 1) | (q >> 2);
        sc8[p] = (q & 3) << 3;
    }
    int erow[2], ec[2], epos[2];
#pragma unroll
    for (int p = 0; p < 2; ++p) {
        int u = p * 256 + t;
        erow[p] = u >> 2; ec[p] = u & 3;
        epos[p] = cf_pos(erow[p], ec[p]) * 8;
    }
    int aoff[4], boff[4];
#pragma unroll
    for (int i = 0; i < 4; ++i) {
        aoff[i] = cf_pos(wm * 64 + i * 16 + lr, lc) * 8;
        boff[i] = cf_pos(wn * 64 + i * 16 + lr, lc) * 8;
    }
    auto stage = [&](int buf, int s) {
        int aa = a0 + (s >> 4), kk = (s & 15) * 32;
#pragma unroll
        for (int p = 0; p < 2; ++p) {
            const float* sp = attrf + ((size_t)(m0 + erow[p]) * NA + aa) * NE + kk + ec[p] * 8;
            float4 v0 = ((const float4*)sp)[0];
            float4 v1 = ((const float4*)sp)[1];
            u16x8 ov = {cvt_bf16(v0.x), cvt_bf16(v0.y), cvt_bf16(v0.z), cvt_bf16(v0.w),
                        cvt_bf16(v1.x), cvt_bf16(v1.y), cvt_bf16(v1.z), cvt_bf16(v1.w)};
            *(u16x8*)&lA[buf][epos[p]] = ov;
        }
#pragma unroll
        for (int p = 0; p < 2; ++p)
            gl_lds16(bwdT + (size_t)(aa * NE + jb + srow[p]) * NE + kk + sc8[p],
                     &lB[buf][(p * 256 + t) * 8]);
    };
    f32x4 res[4][4] = {};
    f32x4 acc[4][4] = {};
    stage(0, 0);
    for (int s = 0; s < 64; ++s) {
        int cur = s & 1;
        __syncthreads();
        if (s < 63) stage(cur ^ 1, s + 1);
        bf16x8 af[4], bfr[4];
#pragma unroll
        for (int i = 0; i < 4; ++i) af[i] = *(const bf16x8*)&lA[cur][aoff[i]];
#pragma unroll
        for (int j = 0; j < 4; ++j) bfr[j] = *(const bf16x8*)&lB[cur][boff[j]];
#pragma unroll
        for (int i = 0; i < 4; ++i)
#pragma unroll
            for (int j = 0; j < 4; ++j)
                acc[i][j] = __builtin_amdgcn_mfma_f32_16x16x32_bf16(af[i], bfr[j], acc[i][j], 0, 0, 0);
        if ((s & 15) == 15) {
            float wa = sw[a0 + (s >> 4)];
#pragma unroll
            for (int i = 0; i < 4; ++i)
#pragma unroll
                for (int j = 0; j < 4; ++j) {
#pragma unroll
                    for (int r = 0; r < 4; ++r)
                        res[i][j][r] += wa * fmaxf(acc[i][j][r], 0.f);
                    acc[i][j] = (f32x4){0.f, 0.f, 0.f, 0.f};
                }
        }
    }
#pragma unroll
    for (int i = 0; i < 4; ++i) {
#pragma unroll
        for (int r = 0; r < 4; ++r) {
            int bm = m0 + wm * 64 + i * 16 + lc * 4 + r;
            float* orow = ind + (size_t)bm * NE + jb;
#pragma unroll
            for (int j = 0; j < 4; ++j)
                atomicAdd(&orow[wn * 64 + j * 16 + lr], res[i][j][r]);
        }
    }
}

extern "C" void kernel_launch(void* const* d_in, const int* in_sizes, int n_in,
                              void* d_out, int out_size, void* d_ws, size_t ws_size,
                              hipStream_t stream) {
    (void)in_sizes; (void)n_in; (void)out_size; (void)ws_size;
    const float* img  = (const float*)d_in[0];
    const float* edge = (const float*)d_in[1];
    const float* lw   = (const float*)d_in[2];
    const float* lb   = (const float*)d_in[3];
    const float* fwd  = (const float*)d_in[4];
    const float* bwd  = (const float*)d_in[5];
    const float* sw   = (const float*)d_in[6];
    float* attr = (float*)d_out;
    float* ind  = attr + (size_t)NB * NA * NE;

    char* ws = (char*)d_ws;
    size_t off = 0;
    auto alloc = [&](size_t bytes) { void* p = ws + off; off += bytes; return p; };
    uint16_t* lwT  = (uint16_t*)alloc((size_t)NK * NE * 2);       // 1 MB
    uint16_t* fwdT = (uint16_t*)alloc((size_t)NA * NE * NE * 2);  // 4 MB
    uint16_t* bwdT = (uint16_t*)alloc((size_t)NA * NE * NE * 2);  // 4 MB
    uint16_t* TMT  = (uint16_t*)alloc((size_t)NN * NK * 2);       // 8 MB
    uint16_t* imgb = (uint16_t*)alloc((size_t)NB * NE * 2);       // 16 MB
    float*    bvec = (float*)alloc((size_t)NN * 4);               // 16 KB

    hipMemsetAsync(bvec, 0, (size_t)NN * 4, stream);
    hipMemsetAsync(ind, 0, (size_t)NB * NE * 4, stream);

    k_pre<<<12928, 256, 0, stream>>>(lw, fwd, bwd, img, lb, lwT, fwdT, bwdT, imgb, bvec);
    k_prep<<<(NK / 128) * (NN / 128), 256, 0, stream>>>(lwT, fwdT, TMT);

    int mm_grid = 8 * 2 * (NB / 128);            // 2048 blocks of 512 threads
    int ind_grid = (NB / 128) * (NE / 128) * 2;  // 1024 blocks of 256 threads

    k_mm4<<<mm_grid, 512, 0, stream>>>(imgb, edge, TMT, bvec, attr);
    k_ind4<<<ind_grid, 256, 0, stream>>>(attr, bwdT, sw, ind);
}

// Round 10
// 477.755 us; speedup vs baseline: 1.0660x; 1.0473x over previous
//
#include <hip/hip_runtime.h>
#include <cstdint>
#include <cstddef>

#define NB 16384
#define NA 8
#define NE 512
#define NK 1024   // 2E
#define NN 4096   // A*E

typedef __bf16 bf16x8 __attribute__((ext_vector_type(8)));
typedef float  f32x4  __attribute__((ext_vector_type(4)));
typedef uint16_t u16x8 __attribute__((ext_vector_type(8)));

__device__ __forceinline__ uint16_t cvt_bf16(float f) {
    uint32_t u = __builtin_bit_cast(uint32_t, f);
    u += 0x7fffu + ((u >> 16) & 1u);
    return (uint16_t)(u >> 16);
}

// legacy BK=32 chunk swizzle (k_prep only)
__device__ __forceinline__ int swz(int row) { return (row ^ (row >> 2)) & 3; }

// conflict-free BK=32 tile position (16B units): row-pair interleave + 3-bit XOR
// proven 0-conflict in R5/R6/R7/R9 PMC
__device__ __forceinline__ int cf_pos(int row, int c) {
    return ((row >> 1) << 3) + ((((row & 1) << 2) + c) ^ ((row >> 1) & 7));
}

__device__ __forceinline__ void gl_lds16(const void* g, void* l) {
    __builtin_amdgcn_global_load_lds(
        (__attribute__((address_space(1))) void*)(void*)g,
        (__attribute__((address_space(3))) void*)l, 16, 0, 0);
}

// ---- fused prep: lw/fwd/bwd transpose-cvt + img cvt + bvec, one launch ----
__device__ __forceinline__ void tcvt_tile(const float* __restrict__ src,
                                          uint16_t* __restrict__ dst,
                                          int R, int C, int c0, int r0, int t) {
    __shared__ float tile[32][33];
    int tx = t & 31, ty = t >> 5;
#pragma unroll
    for (int yy = 0; yy < 4; ++yy) {
        int r = ty + yy * 8;
        tile[r][tx] = src[(size_t)(r0 + r) * C + c0 + tx];
    }
    __syncthreads();
#pragma unroll
    for (int yy = 0; yy < 4; ++yy) {
        int c = ty + yy * 8;
        dst[(size_t)(c0 + c) * R + r0 + tx] = cvt_bf16(tile[tx][c]);
    }
}

__global__ __launch_bounds__(256) void k_pre(const float* __restrict__ lw,
                                             const float* __restrict__ fwd,
                                             const float* __restrict__ bwd,
                                             const float* __restrict__ img,
                                             const float* __restrict__ lb,
                                             uint16_t* __restrict__ lwT,
                                             uint16_t* __restrict__ fwdT,
                                             uint16_t* __restrict__ bwdT,
                                             uint16_t* __restrict__ imgb,
                                             float* __restrict__ bvec) {
    int b = blockIdx.x, t = threadIdx.x;
    if (b < 512) {                       // lw: [512][1024] -> lwT [1024][512]
        int bx = b & 31, by = b >> 5;
        tcvt_tile(lw, lwT, NE, NK, bx * 32, by * 32, t);
    } else if (b < 2560) {               // fwd: 8 mats [512][512] -> [j][i]
        int i = b - 512;
        int mat = i >> 8, bx = i & 15, by = (i >> 4) & 15;
        tcvt_tile(fwd + (size_t)mat * NE * NE, fwdT + (size_t)mat * NE * NE,
                  NE, NE, bx * 32, by * 32, t);
    } else if (b < 4608) {               // bwd
        int i = b - 2560;
        int mat = i >> 8, bx = i & 15, by = (i >> 4) & 15;
        tcvt_tile(bwd + (size_t)mat * NE * NE, bwdT + (size_t)mat * NE * NE,
                  NE, NE, bx * 32, by * 32, t);
    } else if (b < 12800) {              // img f32 -> bf16, 4/thread
        int i = (b - 4608) * 256 + t;
        float4 v = ((const float4*)img)[i];
        ushort4 o;
        o.x = cvt_bf16(v.x); o.y = cvt_bf16(v.y); o.z = cvt_bf16(v.z); o.w = cvt_bf16(v.w);
        ((ushort4*)imgb)[i] = o;
    } else {                             // bvec partials (bvec pre-zeroed)
        int i = b - 12800;
        int a = i >> 4, i0 = (i & 15) * 32;
        float s0 = 0.f, s1 = 0.f;
#pragma unroll 4
        for (int k = 0; k < 32; ++k) {
            float w = lb[i0 + k];
            const float* f = fwd + ((size_t)a * NE + i0 + k) * NE;
            s0 = fmaf(w, f[t], s0);
            s1 = fmaf(w, f[t + 256], s1);
        }
        atomicAdd(&bvec[a * NE + t], s0);
        atomicAdd(&bvec[a * NE + t + 256], s1);
    }
}

// TM[m=k'(1024)][n=(a,j)(4096)] = sum_i lwT[m][i]*fwdT[n][i]; store TMT[n][m] bf16
__global__ __launch_bounds__(256) void k_prep(const uint16_t* __restrict__ lwT,
                                              const uint16_t* __restrict__ fwdT,
                                              uint16_t* __restrict__ TMT) {
    __shared__ alignas(16) uint16_t lA[128 * 32];
    __shared__ alignas(16) uint16_t lB[128 * 32];
    int bz = blockIdx.x;
    int nt = bz & 31, mt = bz >> 5;
    int m0 = mt * 128, n0 = nt * 128;
    int t = threadIdx.x, lane = t & 63;
    int w = t >> 6, wm = w >> 1, wn = w & 1;
    int lr = lane & 15, lc = lane >> 4;
    int sl = swz(lr);
    f32x4 acc[4][4] = {};
    for (int k0 = 0; k0 < NE; k0 += 32) {
        __syncthreads();
#pragma unroll
        for (int p = 0; p < 2; ++p) {
            int idx = p * 256 + t;
            int row = idx >> 2, c16 = (idx & 3) ^ swz(row);
            gl_lds16(lwT + (size_t)(m0 + row) * NE + k0 + c16 * 8, lA + idx * 8);
            gl_lds16(fwdT + (size_t)(n0 + row) * NE + k0 + c16 * 8, lB + idx * 8);
        }
        __syncthreads();
        bf16x8 af[4], bfr[4];
#pragma unroll
        for (int i = 0; i < 4; ++i)
            af[i] = *(const bf16x8*)&lA[(wm * 64 + i * 16 + lr) * 32 + ((lc ^ sl) << 3)];
#pragma unroll
        for (int j = 0; j < 4; ++j)
            bfr[j] = *(const bf16x8*)&lB[(wn * 64 + j * 16 + lr) * 32 + ((lc ^ sl) << 3)];
#pragma unroll
        for (int i = 0; i < 4; ++i)
#pragma unroll
            for (int j = 0; j < 4; ++j)
                acc[i][j] = __builtin_amdgcn_mfma_f32_16x16x32_bf16(af[i], bfr[j], acc[i][j], 0, 0, 0);
    }
#pragma unroll
    for (int i = 0; i < 4; ++i) {
        int mb = m0 + wm * 64 + i * 16 + lc * 4;
#pragma unroll
        for (int j = 0; j < 4; ++j) {
            int n = n0 + wn * 64 + j * 16 + lr;
            ushort4 v;
            v.x = cvt_bf16(acc[i][j][0]);
            v.y = cvt_bf16(acc[i][j][1]);
            v.z = cvt_bf16(acc[i][j][2]);
            v.w = cvt_bf16(acc[i][j][3]);
            *(ushort4*)&TMT[(size_t)n * NK + mb] = v;
        }
    }
}

// attr[b,a,j] = img[b]@TM_a[0:512] + edge[b,a]@TM_a[512:1024] + bvec_a[j]
// R7 structure: 512 thr / 8 waves, 128x256 tile, BK=32 dbuf, cf_pos layout,
// a=XCD, fused edge f32 (T14 load-early / cvt+ds_write-late). Writes attrb bf16.
template<bool WB>
__global__ __launch_bounds__(512) void k_mm4(const uint16_t* __restrict__ imgb,
                                             const float* __restrict__ edge,
                                             const uint16_t* __restrict__ TMT,
                                             const float* __restrict__ bvec,
                                             float* __restrict__ attr,
                                             uint16_t* __restrict__ attrb) {
    __shared__ alignas(16) uint16_t lA[2][128 * 32];   // 2 x 8 KB
    __shared__ alignas(16) uint16_t lB[2][256 * 32];   // 2 x 16 KB
    int o = blockIdx.x;             // 2048 = 8 xcd * (2 jt * 128 mt)
    int a = o & 7, idx = o >> 3;
    int jt = idx & 1, mt = idx >> 1;
    int m0 = mt * 128, jb = jt * 256;
    int t = threadIdx.x, lane = t & 63;
    int w = t >> 6, wm = w >> 2, wn = w & 3;
    int lr = lane & 15, lc = lane >> 4;
    int rpA = t >> 3, qA = (t & 7) ^ (rpA & 7);
    int srA = (rpA << 1) | (qA >> 2), scA = (qA & 3) << 3;
    int srB[2], scB[2];
#pragma unroll
    for (int p = 0; p < 2; ++p) {
        int u = t + p * 512;
        int rp = u >> 3, q = (u & 7) ^ (rp & 7);
        srB[p] = (rp << 1) | (q >> 2);
        scB[p] = (q & 3) << 3;
    }
    int er = t >> 2, ec = t & 3;
    int epos = cf_pos(er, ec) * 8;
    int aoff[4], boff[4];
#pragma unroll
    for (int i = 0; i < 4; ++i) {
        aoff[i] = cf_pos(wm * 64 + i * 16 + lr, lc) * 8;
        boff[i] = cf_pos(wn * 64 + i * 16 + lr, lc) * 8;
    }
    auto stage_img = [&](int buf, int s) {
        gl_lds16(imgb + (size_t)(m0 + srA) * NE + s * 32 + scA, &lA[buf][t * 8]);
    };
    auto stage_tmt = [&](int buf, int s) {
#pragma unroll
        for (int p = 0; p < 2; ++p)
            gl_lds16(TMT + (size_t)(a * NE + jb + srB[p]) * NK + s * 32 + scB[p],
                     &lB[buf][(t + p * 512) * 8]);
    };
    f32x4 acc[4][4] = {};
    stage_img(0, 0);
    stage_tmt(0, 0);
    for (int s = 0; s < 32; ++s) {
        int cur = s & 1, nb = cur ^ 1;
        __syncthreads();
        float4 e0, e1;
        bool eN = (s < 31) && (s + 1 >= 16);
        if (s < 31) {
            if (s + 1 < 16) {
                stage_img(nb, s + 1);
            } else {
                int kk = (s + 1 - 16) * 32;
                const float* sp = edge + ((size_t)(m0 + er) * NA + a) * NE + kk + ec * 8;
                e0 = ((const float4*)sp)[0];
                e1 = ((const float4*)sp)[1];
            }
            stage_tmt(nb, s + 1);
        }
        bf16x8 af[4], bfr[4];
#pragma unroll
        for (int i = 0; i < 4; ++i) af[i] = *(const bf16x8*)&lA[cur][aoff[i]];
#pragma unroll
        for (int j = 0; j < 4; ++j) bfr[j] = *(const bf16x8*)&lB[cur][boff[j]];
#pragma unroll
        for (int i = 0; i < 4; ++i)
#pragma unroll
            for (int j = 0; j < 4; ++j)
                acc[i][j] = __builtin_amdgcn_mfma_f32_16x16x32_bf16(af[i], bfr[j], acc[i][j], 0, 0, 0);
        if (eN) {
            u16x8 ov = {cvt_bf16(e0.x), cvt_bf16(e0.y), cvt_bf16(e0.z), cvt_bf16(e0.w),
                        cvt_bf16(e1.x), cvt_bf16(e1.y), cvt_bf16(e1.z), cvt_bf16(e1.w)};
            *(u16x8*)&lA[nb][epos] = ov;
        }
    }
#pragma unroll
    for (int j = 0; j < 4; ++j) {
        float bv = bvec[a * NE + jb + wn * 64 + j * 16 + lr];
#pragma unroll
        for (int i = 0; i < 4; ++i)
#pragma unroll
            for (int r = 0; r < 4; ++r)
                acc[i][j][r] += bv;
    }
#pragma unroll
    for (int i = 0; i < 4; ++i) {
#pragma unroll
        for (int r = 0; r < 4; ++r) {
            int bm = m0 + wm * 64 + i * 16 + lc * 4 + r;
            float* orow = attr + ((size_t)bm * NA + a) * NE + jb;
#pragma unroll
            for (int j = 0; j < 4; ++j)
                orow[wn * 64 + j * 16 + lr] = acc[i][j][r];
            if (WB) {
                uint16_t* brw = attrb + ((size_t)bm * NA + a) * NE + jb;
#pragma unroll
                for (int j = 0; j < 4; ++j)
                    brw[wn * 64 + j * 16 + lr] = cvt_bf16(acc[i][j][r]);
            }
        }
    }
}

// ind[b,j] += sum_{a in half} sw[a]*relu(attrb[b,a,:]@bwd_a[:,j])
// 512 thr / 8 waves, 128x256 tile, BK=32 dbuf, cf_pos, a-split-2 atomics.
// attrb via gl_lds (async); f32 fallback staged via regs.
template<bool AB>
__global__ __launch_bounds__(512) void k_ind5(const float* __restrict__ attrf,
                                              const uint16_t* __restrict__ attrb,
                                              const uint16_t* __restrict__ bwdT,
                                              const float* __restrict__ sw,
                                              float* __restrict__ ind) {
    __shared__ alignas(16) uint16_t lA[2][128 * 32];   // 2 x 8 KB
    __shared__ alignas(16) uint16_t lB[2][256 * 32];   // 2 x 16 KB
    int o = blockIdx.x;             // 512 = (128 mt) * (2 jt) * (2 ah)
    int ah = o & 1, jt = (o >> 1) & 1, mt = o >> 2;
    int m0 = mt * 128, jb = jt * 256, a0 = ah * 4;
    int t = threadIdx.x, lane = t & 63;
    int w = t >> 6, wm = w >> 2, wn = w & 3;
    int lr = lane & 15, lc = lane >> 4;
    // A stage map (1 unit/thread), inverse cf_pos
    int rpA = t >> 3, qA = (t & 7) ^ (rpA & 7);
    int srA = (rpA << 1) | (qA >> 2), scA = (qA & 3) << 3;
    // B stage map (2 units/thread)
    int srB[2], scB[2];
#pragma unroll
    for (int p = 0; p < 2; ++p) {
        int u = t + p * 512;
        int rp = u >> 3, q = (u & 7) ^ (rp & 7);
        srB[p] = (rp << 1) | (q >> 2);
        scB[p] = (q & 3) << 3;
    }
    // f32 fallback: thread owns (row, chunk) natural, writes swizzled
    int er = t >> 2, ec = t & 3;
    int epos = cf_pos(er, ec) * 8;
    int aoff[4], boff[4];
#pragma unroll
    for (int i = 0; i < 4; ++i) {
        aoff[i] = cf_pos(wm * 64 + i * 16 + lr, lc) * 8;
        boff[i] = cf_pos(wn * 64 + i * 16 + lr, lc) * 8;
    }
    auto stage = [&](int buf, int s) {
        int aa = a0 + (s >> 4), kk = (s & 15) * 32;
        if (AB) {
            gl_lds16(attrb + ((size_t)(m0 + srA) * NA + aa) * NE + kk + scA,
                     &lA[buf][t * 8]);
        } else {
            const float* sp = attrf + ((size_t)(m0 + er) * NA + aa) * NE + kk + ec * 8;
            float4 v0 = ((const float4*)sp)[0];
            float4 v1 = ((const float4*)sp)[1];
            u16x8 ov = {cvt_bf16(v0.x), cvt_bf16(v0.y), cvt_bf16(v0.z), cvt_bf16(v0.w),
                        cvt_bf16(v1.x), cvt_bf16(v1.y), cvt_bf16(v1.z), cvt_bf16(v1.w)};
            *(u16x8*)&lA[buf][epos] = ov;
        }
#pragma unroll
        for (int p = 0; p < 2; ++p)
            gl_lds16(bwdT + (size_t)(aa * NE + jb + srB[p]) * NE + kk + scB[p],
                     &lB[buf][(t + p * 512) * 8]);
    };
    f32x4 res[4][4] = {};
    f32x4 acc[4][4] = {};
    stage(0, 0);
    for (int s = 0; s < 64; ++s) {
        int cur = s & 1;
        __syncthreads();
        if (s < 63) stage(cur ^ 1, s + 1);
        bf16x8 af[4], bfr[4];
#pragma unroll
        for (int i = 0; i < 4; ++i) af[i] = *(const bf16x8*)&lA[cur][aoff[i]];
#pragma unroll
        for (int j = 0; j < 4; ++j) bfr[j] = *(const bf16x8*)&lB[cur][boff[j]];
#pragma unroll
        for (int i = 0; i < 4; ++i)
#pragma unroll
            for (int j = 0; j < 4; ++j)
                acc[i][j] = __builtin_amdgcn_mfma_f32_16x16x32_bf16(af[i], bfr[j], acc[i][j], 0, 0, 0);
        if ((s & 15) == 15) {
            float wa = sw[a0 + (s >> 4)];
#pragma unroll
            for (int i = 0; i < 4; ++i)
#pragma unroll
                for (int j = 0; j < 4; ++j) {
#pragma unroll
                    for (int r = 0; r < 4; ++r)
                        res[i][j][r] += wa * fmaxf(acc[i][j][r], 0.f);
                    acc[i][j] = (f32x4){0.f, 0.f, 0.f, 0.f};
                }
        }
    }
#pragma unroll
    for (int i = 0; i < 4; ++i) {
#pragma unroll
        for (int r = 0; r < 4; ++r) {
            int bm = m0 + wm * 64 + i * 16 + lc * 4 + r;
            float* orow = ind + (size_t)bm * NE + jb;
#pragma unroll
            for (int j = 0; j < 4; ++j)
                atomicAdd(&orow[wn * 64 + j * 16 + lr], res[i][j][r]);
        }
    }
}

extern "C" void kernel_launch(void* const* d_in, const int* in_sizes, int n_in,
                              void* d_out, int out_size, void* d_ws, size_t ws_size,
                              hipStream_t stream) {
    (void)in_sizes; (void)n_in; (void)out_size;
    const float* img  = (const float*)d_in[0];
    const float* edge = (const float*)d_in[1];
    const float* lw   = (const float*)d_in[2];
    const float* lb   = (const float*)d_in[3];
    const float* fwd  = (const float*)d_in[4];
    const float* bwd  = (const float*)d_in[5];
    const float* sw   = (const float*)d_in[6];
    float* attr = (float*)d_out;
    float* ind  = attr + (size_t)NB * NA * NE;

    char* ws = (char*)d_ws;
    size_t off = 0;
    auto alloc = [&](size_t bytes) { void* p = ws + off; off += bytes; return p; };
    uint16_t* lwT  = (uint16_t*)alloc((size_t)NK * NE * 2);       // 1 MB
    uint16_t* fwdT = (uint16_t*)alloc((size_t)NA * NE * NE * 2);  // 4 MB
    uint16_t* bwdT = (uint16_t*)alloc((size_t)NA * NE * NE * 2);  // 4 MB
    uint16_t* TMT  = (uint16_t*)alloc((size_t)NN * NK * 2);       // 8 MB
    uint16_t* imgb = (uint16_t*)alloc((size_t)NB * NE * 2);       // 16 MB
    float*    bvec = (float*)alloc((size_t)NN * 4);               // 16 KB

    const size_t BIGB = (size_t)NB * NA * NE * 2;  // 128 MB
    bool has_attrb = ws_size >= off + BIGB;
    uint16_t* attrb = has_attrb ? (uint16_t*)alloc(BIGB) : (uint16_t*)0;

    hipMemsetAsync(bvec, 0, (size_t)NN * 4, stream);
    hipMemsetAsync(ind, 0, (size_t)NB * NE * 4, stream);

    k_pre<<<12928, 256, 0, stream>>>(lw, fwd, bwd, img, lb, lwT, fwdT, bwdT, imgb, bvec);
    k_prep<<<(NK / 128) * (NN / 128), 256, 0, stream>>>(lwT, fwdT, TMT);

    int mm_grid = 8 * 2 * (NB / 128);        // 2048 blocks of 512 threads
    int ind_grid = (NB / 128) * 2 * 2;       // 512 blocks of 512 threads

    if (has_attrb) {
        k_mm4<true><<<mm_grid, 512, 0, stream>>>(imgb, edge, TMT, bvec, attr, attrb);
        k_ind5<true><<<ind_grid, 512, 0, stream>>>(attr, attrb, bwdT, sw, ind);
    } else {
        k_mm4<false><<<mm_grid, 512, 0, stream>>>(imgb, edge, TMT, bvec, attr, attrb);
        k_ind5<false><<<ind_grid, 512, 0, stream>>>(attr, attrb, bwdT, sw, ind);
    }
}

// Round 11
// 476.940 us; speedup vs baseline: 1.0678x; 1.0017x over previous
//
#include <hip/hip_runtime.h>
#include <cstdint>
#include <cstddef>

#define NB 16384
#define NA 8
#define NE 512
#define NK 1024   // 2E
#define NN 4096   // A*E

typedef __bf16 bf16x8 __attribute__((ext_vector_type(8)));
typedef float  f32x4  __attribute__((ext_vector_type(4)));
typedef uint16_t u16x8 __attribute__((ext_vector_type(8)));

__device__ __forceinline__ uint16_t cvt_bf16(float f) {
    uint32_t u = __builtin_bit_cast(uint32_t, f);
    u += 0x7fffu + ((u >> 16) & 1u);
    return (uint16_t)(u >> 16);
}

// legacy BK=32 chunk swizzle (k_prep only)
__device__ __forceinline__ int swz(int row) { return (row ^ (row >> 2)) & 3; }

// conflict-free BK=32 tile position (16B units): row-pair interleave + 3-bit XOR
// proven 0-conflict in R5..R10 PMC
__device__ __forceinline__ int cf_pos(int row, int c) {
    return ((row >> 1) << 3) + ((((row & 1) << 2) + c) ^ ((row >> 1) & 7));
}

__device__ __forceinline__ void gl_lds16(const void* g, void* l) {
    __builtin_amdgcn_global_load_lds(
        (__attribute__((address_space(1))) void*)(void*)g,
        (__attribute__((address_space(3))) void*)l, 16, 0, 0);
}

// ---- fused prep: lw/fwd/bwd transpose-cvt + img cvt + bvec, one launch ----
__device__ __forceinline__ void tcvt_tile(const float* __restrict__ src,
                                          uint16_t* __restrict__ dst,
                                          int R, int C, int c0, int r0, int t) {
    __shared__ float tile[32][33];
    int tx = t & 31, ty = t >> 5;
#pragma unroll
    for (int yy = 0; yy < 4; ++yy) {
        int r = ty + yy * 8;
        tile[r][tx] = src[(size_t)(r0 + r) * C + c0 + tx];
    }
    __syncthreads();
#pragma unroll
    for (int yy = 0; yy < 4; ++yy) {
        int c = ty + yy * 8;
        dst[(size_t)(c0 + c) * R + r0 + tx] = cvt_bf16(tile[tx][c]);
    }
}

__global__ __launch_bounds__(256) void k_pre(const float* __restrict__ lw,
                                             const float* __restrict__ fwd,
                                             const float* __restrict__ bwd,
                                             const float* __restrict__ img,
                                             const float* __restrict__ lb,
                                             uint16_t* __restrict__ lwT,
                                             uint16_t* __restrict__ fwdT,
                                             uint16_t* __restrict__ bwdT,
                                             uint16_t* __restrict__ imgb,
                                             float* __restrict__ bvec) {
    int b = blockIdx.x, t = threadIdx.x;
    if (b < 512) {
        int bx = b & 31, by = b >> 5;
        tcvt_tile(lw, lwT, NE, NK, bx * 32, by * 32, t);
    } else if (b < 2560) {
        int i = b - 512;
        int mat = i >> 8, bx = i & 15, by = (i >> 4) & 15;
        tcvt_tile(fwd + (size_t)mat * NE * NE, fwdT + (size_t)mat * NE * NE,
                  NE, NE, bx * 32, by * 32, t);
    } else if (b < 4608) {
        int i = b - 2560;
        int mat = i >> 8, bx = i & 15, by = (i >> 4) & 15;
        tcvt_tile(bwd + (size_t)mat * NE * NE, bwdT + (size_t)mat * NE * NE,
                  NE, NE, bx * 32, by * 32, t);
    } else if (b < 12800) {
        int i = (b - 4608) * 256 + t;
        float4 v = ((const float4*)img)[i];
        ushort4 o;
        o.x = cvt_bf16(v.x); o.y = cvt_bf16(v.y); o.z = cvt_bf16(v.z); o.w = cvt_bf16(v.w);
        ((ushort4*)imgb)[i] = o;
    } else {
        int i = b - 12800;
        int a = i >> 4, i0 = (i & 15) * 32;
        float s0 = 0.f, s1 = 0.f;
#pragma unroll 4
        for (int k = 0; k < 32; ++k) {
            float w = lb[i0 + k];
            const float* f = fwd + ((size_t)a * NE + i0 + k) * NE;
            s0 = fmaf(w, f[t], s0);
            s1 = fmaf(w, f[t + 256], s1);
        }
        atomicAdd(&bvec[a * NE + t], s0);
        atomicAdd(&bvec[a * NE + t + 256], s1);
    }
}

// TM[m=k'(1024)][n=(a,j)(4096)] = sum_i lwT[m][i]*fwdT[n][i]; store TMT[n][m] bf16
__global__ __launch_bounds__(256) void k_prep(const uint16_t* __restrict__ lwT,
                                              const uint16_t* __restrict__ fwdT,
                                              uint16_t* __restrict__ TMT) {
    __shared__ alignas(16) uint16_t lA[128 * 32];
    __shared__ alignas(16) uint16_t lB[128 * 32];
    int bz = blockIdx.x;
    int nt = bz & 31, mt = bz >> 5;
    int m0 = mt * 128, n0 = nt * 128;
    int t = threadIdx.x, lane = t & 63;
    int w = t >> 6, wm = w >> 1, wn = w & 1;
    int lr = lane & 15, lc = lane >> 4;
    int sl = swz(lr);
    f32x4 acc[4][4] = {};
    for (int k0 = 0; k0 < NE; k0 += 32) {
        __syncthreads();
#pragma unroll
        for (int p = 0; p < 2; ++p) {
            int idx = p * 256 + t;
            int row = idx >> 2, c16 = (idx & 3) ^ swz(row);
            gl_lds16(lwT + (size_t)(m0 + row) * NE + k0 + c16 * 8, lA + idx * 8);
            gl_lds16(fwdT + (size_t)(n0 + row) * NE + k0 + c16 * 8, lB + idx * 8);
        }
        __syncthreads();
        bf16x8 af[4], bfr[4];
#pragma unroll
        for (int i = 0; i < 4; ++i)
            af[i] = *(const bf16x8*)&lA[(wm * 64 + i * 16 + lr) * 32 + ((lc ^ sl) << 3)];
#pragma unroll
        for (int j = 0; j < 4; ++j)
            bfr[j] = *(const bf16x8*)&lB[(wn * 64 + j * 16 + lr) * 32 + ((lc ^ sl) << 3)];
#pragma unroll
        for (int i = 0; i < 4; ++i)
#pragma unroll
            for (int j = 0; j < 4; ++j)
                acc[i][j] = __builtin_amdgcn_mfma_f32_16x16x32_bf16(af[i], bfr[j], acc[i][j], 0, 0, 0);
    }
#pragma unroll
    for (int i = 0; i < 4; ++i) {
        int mb = m0 + wm * 64 + i * 16 + lc * 4;
#pragma unroll
        for (int j = 0; j < 4; ++j) {
            int n = n0 + wn * 64 + j * 16 + lr;
            ushort4 v;
            v.x = cvt_bf16(acc[i][j][0]);
            v.y = cvt_bf16(acc[i][j][1]);
            v.z = cvt_bf16(acc[i][j][2]);
            v.w = cvt_bf16(acc[i][j][3]);
            *(ushort4*)&TMT[(size_t)n * NK + mb] = v;
        }
    }
}

// attr GEMM with counted-vmcnt 2-phase schedule (T3-min + T4).
// 512 thr / 8 waves, 128x256 tile, BK=32 dbuf, cf_pos layout, a=XCD,
// edge f32 loaded one step ahead into ping-pong regs (T14), cvt+ds_write post-MFMA.
// vmcnt ledger: 3 stage-loads/step -> vmcnt(3) at phase top; peeled tail 2/0.
template<bool WB>
__global__ __launch_bounds__(512) void k_mm6(const uint16_t* __restrict__ imgb,
                                             const float* __restrict__ edge,
                                             const uint16_t* __restrict__ TMT,
                                             const float* __restrict__ bvec,
                                             float* __restrict__ attr,
                                             uint16_t* __restrict__ attrb) {
    __shared__ alignas(16) uint16_t lA[2][128 * 32];   // 2 x 8 KB
    __shared__ alignas(16) uint16_t lB[2][256 * 32];   // 2 x 16 KB
    int o = blockIdx.x;             // 2048 = 8 xcd * (2 jt * 128 mt)
    int a = o & 7, idx = o >> 3;
    int jt = idx & 1, mt = idx >> 1;
    int m0 = mt * 128, jb = jt * 256;
    int t = threadIdx.x, lane = t & 63;
    int w = t >> 6, wm = w >> 2, wn = w & 3;
    int lr = lane & 15, lc = lane >> 4;
    // stage source maps (inverse cf_pos)
    int rpA = t >> 3, qA = (t & 7) ^ (rpA & 7);
    int srA = (rpA << 1) | (qA >> 2), scA = (qA & 3) << 3;
    int srB[2], scB[2];
#pragma unroll
    for (int p = 0; p < 2; ++p) {
        int u = t + p * 512;
        int rp = u >> 3, q = (u & 7) ^ (rp & 7);
        srB[p] = (rp << 1) | (q >> 2);
        scB[p] = (q & 3) << 3;
    }
    // edge f32: thread owns (row, chunk) natural, writes swizzled
    int er = t >> 2, ec = t & 3;
    int epos = cf_pos(er, ec) * 8;
    int aoff[4], boff[4];
#pragma unroll
    for (int i = 0; i < 4; ++i) {
        aoff[i] = cf_pos(wm * 64 + i * 16 + lr, lc) * 8;
        boff[i] = cf_pos(wn * 64 + i * 16 + lr, lc) * 8;
    }
    const uint16_t* gA  = imgb + (size_t)(m0 + srA) * NE + scA;
    const uint16_t* gB0 = TMT + (size_t)(a * NE + jb + srB[0]) * NK + scB[0];
    const uint16_t* gB1 = TMT + (size_t)(a * NE + jb + srB[1]) * NK + scB[1];
    const float*    gE  = edge + ((size_t)(m0 + er) * NA + a) * NE + ec * 8;

    f32x4 acc[4][4] = {};
    float4 e[2][2];   // ping-pong edge reg sets; indices static after unroll

#define FRAGS_AND_MFMA(CUR)                                                        \
    {                                                                              \
        bf16x8 af[4], bfr[4];                                                      \
        _Pragma("unroll")                                                          \
        for (int i = 0; i < 4; ++i) af[i] = *(const bf16x8*)&lA[CUR][aoff[i]];     \
        _Pragma("unroll")                                                          \
        for (int j = 0; j < 4; ++j) bfr[j] = *(const bf16x8*)&lB[CUR][boff[j]];    \
        asm volatile("s_waitcnt lgkmcnt(0)" ::: "memory");                         \
        __builtin_amdgcn_sched_barrier(0);                                         \
        _Pragma("unroll")                                                          \
        for (int i = 0; i < 4; ++i)                                                \
            _Pragma("unroll")                                                      \
            for (int j = 0; j < 4; ++j)                                            \
                acc[i][j] = __builtin_amdgcn_mfma_f32_16x16x32_bf16(af[i], bfr[j], acc[i][j], 0, 0, 0); \
    }

    // prologue: stage s=0 -> buf0, s=1 -> buf1 (img region)
    gl_lds16(gA,       &lA[0][t * 8]);
    gl_lds16(gB0,      &lB[0][t * 8]);
    gl_lds16(gB1,      &lB[0][(t + 512) * 8]);
    gl_lds16(gA + 32,  &lA[1][t * 8]);
    gl_lds16(gB0 + 32, &lB[1][t * 8]);
    gl_lds16(gB1 + 32, &lB[1][(t + 512) * 8]);

    // loop1: s = 0..13, stage img for s+2 (<=15); at s==13 preload edge f32 for s=16
#pragma unroll 2
    for (int s = 0; s < 14; ++s) {
        int cur = s & 1;
        asm volatile("s_waitcnt vmcnt(3) lgkmcnt(0)\n\ts_barrier" ::: "memory");
        if (s == 13) {
            e[0][0] = *(const float4*)gE;
            e[0][1] = *(const float4*)(gE + 4);
        }
        FRAGS_AND_MFMA(cur);
        asm volatile("s_barrier" ::: "memory");
        gl_lds16(gA + (s + 2) * 32,  &lA[cur][t * 8]);
        gl_lds16(gB0 + (s + 2) * 32, &lB[cur][t * 8]);
        gl_lds16(gB1 + (s + 2) * 32, &lB[cur][(t + 512) * 8]);
    }

    // loop2: s = 14..29; load F(s+3) early, consume F(s+2) post-MFMA, stage TMT(s+2)
#pragma unroll 2
    for (int s = 14; s < 30; ++s) {
        int cur = s & 1;
        asm volatile("s_waitcnt vmcnt(3) lgkmcnt(0)\n\ts_barrier" ::: "memory");
        if (s < 29) {   // F(s+3), s+3 in [17,31]
            float4* eo = e[(s + 1) & 1];
            eo[0] = *(const float4*)(gE + (s - 13) * 32);
            eo[1] = *(const float4*)(gE + (s - 13) * 32 + 4);
        }
        FRAGS_AND_MFMA(cur);
        asm volatile("s_barrier" ::: "memory");
        {   // A(s+2) from F(s+2) in e[s&1]; write into lA[cur] (free after barrier)
            const float4* ei = e[s & 1];
            u16x8 ov = {cvt_bf16(ei[0].x), cvt_bf16(ei[0].y), cvt_bf16(ei[0].z), cvt_bf16(ei[0].w),
                        cvt_bf16(ei[1].x), cvt_bf16(ei[1].y), cvt_bf16(ei[1].z), cvt_bf16(ei[1].w)};
            *(u16x8*)&lA[cur][epos] = ov;
        }
        gl_lds16(gB0 + (s + 2) * 32, &lB[cur][t * 8]);
        gl_lds16(gB1 + (s + 2) * 32, &lB[cur][(t + 512) * 8]);
    }

    // peeled s=30: only T(30),T(31) outstanding -> need T(30) done: vmcnt(2)
    asm volatile("s_waitcnt vmcnt(2) lgkmcnt(0)\n\ts_barrier" ::: "memory");
    FRAGS_AND_MFMA(0);
    asm volatile("s_barrier" ::: "memory");
    // peeled s=31: drain everything
    asm volatile("s_waitcnt vmcnt(0) lgkmcnt(0)\n\ts_barrier" ::: "memory");
    FRAGS_AND_MFMA(1);
#undef FRAGS_AND_MFMA

#pragma unroll
    for (int j = 0; j < 4; ++j) {
        float bv = bvec[a * NE + jb + wn * 64 + j * 16 + lr];
#pragma unroll
        for (int i = 0; i < 4; ++i)
#pragma unroll
            for (int r = 0; r < 4; ++r)
                acc[i][j][r] += bv;
    }
#pragma unroll
    for (int i = 0; i < 4; ++i) {
#pragma unroll
        for (int r = 0; r < 4; ++r) {
            int bm = m0 + wm * 64 + i * 16 + lc * 4 + r;
            float* orow = attr + ((size_t)bm * NA + a) * NE + jb;
#pragma unroll
            for (int j = 0; j < 4; ++j)
                orow[wn * 64 + j * 16 + lr] = acc[i][j][r];
            if (WB) {
                uint16_t* brw = attrb + ((size_t)bm * NA + a) * NE + jb;
#pragma unroll
                for (int j = 0; j < 4; ++j)
                    brw[wn * 64 + j * 16 + lr] = cvt_bf16(acc[i][j][r]);
            }
        }
    }
}

// ind[b,j] += sum_{a in half} sw[a]*relu(attrb[b,a,:]@bwd_a[:,j])
// R7 winner verbatim: 256 thr, 128x128, BK=32 dbuf, cf_pos, (jt,ah)=XCD, a-split-2.
template<bool AB>
__global__ __launch_bounds__(256) void k_ind4(const float* __restrict__ attrf,
                                              const uint16_t* __restrict__ attrb,
                                              const uint16_t* __restrict__ bwdT,
                                              const float* __restrict__ sw,
                                              float* __restrict__ ind) {
    __shared__ alignas(16) uint16_t lA[2][128 * 32];
    __shared__ alignas(16) uint16_t lB[2][128 * 32];
    int o = blockIdx.x;            // 1024 = 8 xcd * 128 mt
    int xcd = o & 7, mt = o >> 3;
    int jt = xcd >> 1, ah = xcd & 1;
    int m0 = mt * 128, jb = jt * 128, a0 = ah * 4;
    int t = threadIdx.x, lane = t & 63;
    int w = t >> 6, wm = w >> 1, wn = w & 1;
    int lr = lane & 15, lc = lane >> 4;
    int srow[2], sc8[2];
#pragma unroll
    for (int p = 0; p < 2; ++p) {
        int u = p * 256 + t;
        int rp = u >> 3, q = (u & 7) ^ (rp & 7);
        srow[p] = (rp << 1) | (q >> 2);
        sc8[p] = (q & 3) << 3;
    }
    int erow[2], ec[2], epos[2];
#pragma unroll
    for (int p = 0; p < 2; ++p) {
        int u = p * 256 + t;
        erow[p] = u >> 2; ec[p] = u & 3;
        epos[p] = cf_pos(erow[p], ec[p]) * 8;
    }
    int aoff[4], boff[4];
#pragma unroll
    for (int i = 0; i < 4; ++i) {
        aoff[i] = cf_pos(wm * 64 + i * 16 + lr, lc) * 8;
        boff[i] = cf_pos(wn * 64 + i * 16 + lr, lc) * 8;
    }
    auto stage = [&](int buf, int s) {
        int aa = a0 + (s >> 4), kk = (s & 15) * 32;
        if (AB) {
#pragma unroll
            for (int p = 0; p < 2; ++p)
                gl_lds16(attrb + ((size_t)(m0 + srow[p]) * NA + aa) * NE + kk + sc8[p],
                         &lA[buf][(p * 256 + t) * 8]);
        } else {
#pragma unroll
            for (int p = 0; p < 2; ++p) {
                const float* sp = attrf + ((size_t)(m0 + erow[p]) * NA + aa) * NE + kk + ec[p] * 8;
                float4 v0 = ((const float4*)sp)[0];
                float4 v1 = ((const float4*)sp)[1];
                u16x8 ov = {cvt_bf16(v0.x), cvt_bf16(v0.y), cvt_bf16(v0.z), cvt_bf16(v0.w),
                            cvt_bf16(v1.x), cvt_bf16(v1.y), cvt_bf16(v1.z), cvt_bf16(v1.w)};
                *(u16x8*)&lA[buf][epos[p]] = ov;
            }
        }
#pragma unroll
        for (int p = 0; p < 2; ++p)
            gl_lds16(bwdT + (size_t)(aa * NE + jb + srow[p]) * NE + kk + sc8[p],
                     &lB[buf][(p * 256 + t) * 8]);
    };
    f32x4 res[4][4] = {};
    f32x4 acc[4][4] = {};
    stage(0, 0);
    for (int s = 0; s < 64; ++s) {
        int cur = s & 1;
        __syncthreads();
        if (s < 63) stage(cur ^ 1, s + 1);
        bf16x8 af[4], bfr[4];
#pragma unroll
        for (int i = 0; i < 4; ++i) af[i] = *(const bf16x8*)&lA[cur][aoff[i]];
#pragma unroll
        for (int j = 0; j < 4; ++j) bfr[j] = *(const bf16x8*)&lB[cur][boff[j]];
#pragma unroll
        for (int i = 0; i < 4; ++i)
#pragma unroll
            for (int j = 0; j < 4; ++j)
                acc[i][j] = __builtin_amdgcn_mfma_f32_16x16x32_bf16(af[i], bfr[j], acc[i][j], 0, 0, 0);
        if ((s & 15) == 15) {
            float wa = sw[a0 + (s >> 4)];
#pragma unroll
            for (int i = 0; i < 4; ++i)
#pragma unroll
                for (int j = 0; j < 4; ++j) {
#pragma unroll
                    for (int r = 0; r < 4; ++r)
                        res[i][j][r] += wa * fmaxf(acc[i][j][r], 0.f);
                    acc[i][j] = (f32x4){0.f, 0.f, 0.f, 0.f};
                }
        }
    }
#pragma unroll
    for (int i = 0; i < 4; ++i) {
#pragma unroll
        for (int r = 0; r < 4; ++r) {
            int bm = m0 + wm * 64 + i * 16 + lc * 4 + r;
            float* orow = ind + (size_t)bm * NE + jb;
#pragma unroll
            for (int j = 0; j < 4; ++j)
                atomicAdd(&orow[wn * 64 + j * 16 + lr], res[i][j][r]);
        }
    }
}

extern "C" void kernel_launch(void* const* d_in, const int* in_sizes, int n_in,
                              void* d_out, int out_size, void* d_ws, size_t ws_size,
                              hipStream_t stream) {
    (void)in_sizes; (void)n_in; (void)out_size;
    const float* img  = (const float*)d_in[0];
    const float* edge = (const float*)d_in[1];
    const float* lw   = (const float*)d_in[2];
    const float* lb   = (const float*)d_in[3];
    const float* fwd  = (const float*)d_in[4];
    const float* bwd  = (const float*)d_in[5];
    const float* sw   = (const float*)d_in[6];
    float* attr = (float*)d_out;
    float* ind  = attr + (size_t)NB * NA * NE;

    char* ws = (char*)d_ws;
    size_t off = 0;
    auto alloc = [&](size_t bytes) { void* p = ws + off; off += bytes; return p; };
    uint16_t* lwT  = (uint16_t*)alloc((size_t)NK * NE * 2);       // 1 MB
    uint16_t* fwdT = (uint16_t*)alloc((size_t)NA * NE * NE * 2);  // 4 MB
    uint16_t* bwdT = (uint16_t*)alloc((size_t)NA * NE * NE * 2);  // 4 MB
    uint16_t* TMT  = (uint16_t*)alloc((size_t)NN * NK * 2);       // 8 MB
    uint16_t* imgb = (uint16_t*)alloc((size_t)NB * NE * 2);       // 16 MB
    float*    bvec = (float*)alloc((size_t)NN * 4);               // 16 KB

    const size_t BIGB = (size_t)NB * NA * NE * 2;  // 128 MB
    bool has_attrb = ws_size >= off + BIGB;
    uint16_t* attrb = has_attrb ? (uint16_t*)alloc(BIGB) : (uint16_t*)0;

    hipMemsetAsync(bvec, 0, (size_t)NN * 4, stream);
    hipMemsetAsync(ind, 0, (size_t)NB * NE * 4, stream);

    k_pre<<<12928, 256, 0, stream>>>(lw, fwd, bwd, img, lb, lwT, fwdT, bwdT, imgb, bvec);
    k_prep<<<(NK / 128) * (NN / 128), 256, 0, stream>>>(lwT, fwdT, TMT);

    int mm_grid = 8 * 2 * (NB / 128);        // 2048 blocks of 512 threads
    int ind_grid = (NB / 128) * (NE / 128) * 2;  // 1024 blocks of 256 threads

    if (has_attrb) {
        k_mm6<true><<<mm_grid, 512, 0, stream>>>(imgb, edge, TMT, bvec, attr, attrb);
        k_ind4<true><<<ind_grid, 256, 0, stream>>>(attr, attrb, bwdT, sw, ind);
    } else {
        k_mm6<false><<<mm_grid, 512, 0, stream>>>(imgb, edge, TMT, bvec, attr, attrb);
        k_ind4<false><<<ind_grid, 256, 0, stream>>>(attr, attrb, bwdT, sw, ind);
    }
}

// Round 12
// 440.598 us; speedup vs baseline: 1.1559x; 1.0825x over previous
//
#include <hip/hip_runtime.h>
#include <cstdint>
#include <cstddef>

#define NB 16384
#define NA 8
#define NE 512
#define NK 1024   // 2E
#define NN 4096   // A*E

typedef __bf16 bf16x8 __attribute__((ext_vector_type(8)));
typedef float  f32x4  __attribute__((ext_vector_type(4)));
typedef uint16_t u16x8 __attribute__((ext_vector_type(8)));

__device__ __forceinline__ uint16_t cvt_bf16(float f) {
    uint32_t u = __builtin_bit_cast(uint32_t, f);
    u += 0x7fffu + ((u >> 16) & 1u);
    return (uint16_t)(u >> 16);
}

// legacy BK=32 chunk swizzle (k_prep only)
__device__ __forceinline__ int swz(int row) { return (row ^ (row >> 2)) & 3; }

// conflict-free BK=32 tile position (16B units): row-pair interleave + 3-bit XOR
// proven 0-conflict in R5..R11 PMC
__device__ __forceinline__ int cf_pos(int row, int c) {
    return ((row >> 1) << 3) + ((((row & 1) << 2) + c) ^ ((row >> 1) & 7));
}

__device__ __forceinline__ void gl_lds16(const void* g, void* l) {
    __builtin_amdgcn_global_load_lds(
        (__attribute__((address_space(1))) void*)(void*)g,
        (__attribute__((address_space(3))) void*)l, 16, 0, 0);
}

// ---- fused prep: lw/fwd/bwd transpose-cvt + img cvt + bvec, one launch ----
__device__ __forceinline__ void tcvt_tile(const float* __restrict__ src,
                                          uint16_t* __restrict__ dst,
                                          int R, int C, int c0, int r0, int t) {
    __shared__ float tile[32][33];
    int tx = t & 31, ty = t >> 5;
#pragma unroll
    for (int yy = 0; yy < 4; ++yy) {
        int r = ty + yy * 8;
        tile[r][tx] = src[(size_t)(r0 + r) * C + c0 + tx];
    }
    __syncthreads();
#pragma unroll
    for (int yy = 0; yy < 4; ++yy) {
        int c = ty + yy * 8;
        dst[(size_t)(c0 + c) * R + r0 + tx] = cvt_bf16(tile[tx][c]);
    }
}

__global__ __launch_bounds__(256) void k_pre(const float* __restrict__ lw,
                                             const float* __restrict__ fwd,
                                             const float* __restrict__ bwd,
                                             const float* __restrict__ img,
                                             const float* __restrict__ lb,
                                             uint16_t* __restrict__ lwT,
                                             uint16_t* __restrict__ fwdT,
                                             uint16_t* __restrict__ bwdT,
                                             uint16_t* __restrict__ imgb,
                                             float* __restrict__ bvec) {
    int b = blockIdx.x, t = threadIdx.x;
    if (b < 512) {
        int bx = b & 31, by = b >> 5;
        tcvt_tile(lw, lwT, NE, NK, bx * 32, by * 32, t);
    } else if (b < 2560) {
        int i = b - 512;
        int mat = i >> 8, bx = i & 15, by = (i >> 4) & 15;
        tcvt_tile(fwd + (size_t)mat * NE * NE, fwdT + (size_t)mat * NE * NE,
                  NE, NE, bx * 32, by * 32, t);
    } else if (b < 4608) {
        int i = b - 2560;
        int mat = i >> 8, bx = i & 15, by = (i >> 4) & 15;
        tcvt_tile(bwd + (size_t)mat * NE * NE, bwdT + (size_t)mat * NE * NE,
                  NE, NE, bx * 32, by * 32, t);
    } else if (b < 12800) {
        int i = (b - 4608) * 256 + t;
        float4 v = ((const float4*)img)[i];
        ushort4 o;
        o.x = cvt_bf16(v.x); o.y = cvt_bf16(v.y); o.z = cvt_bf16(v.z); o.w = cvt_bf16(v.w);
        ((ushort4*)imgb)[i] = o;
    } else {
        int i = b - 12800;
        int a = i >> 4, i0 = (i & 15) * 32;
        float s0 = 0.f, s1 = 0.f;
#pragma unroll 4
        for (int k = 0; k < 32; ++k) {
            float w = lb[i0 + k];
            const float* f = fwd + ((size_t)a * NE + i0 + k) * NE;
            s0 = fmaf(w, f[t], s0);
            s1 = fmaf(w, f[t + 256], s1);
        }
        atomicAdd(&bvec[a * NE + t], s0);
        atomicAdd(&bvec[a * NE + t + 256], s1);
    }
}

// TM[m=k'(1024)][n=(a,j)(4096)] = sum_i lwT[m][i]*fwdT[n][i]; store TMT[n][m] bf16
__global__ __launch_bounds__(256) void k_prep(const uint16_t* __restrict__ lwT,
                                              const uint16_t* __restrict__ fwdT,
                                              uint16_t* __restrict__ TMT) {
    __shared__ alignas(16) uint16_t lA[128 * 32];
    __shared__ alignas(16) uint16_t lB[128 * 32];
    int bz = blockIdx.x;
    int nt = bz & 31, mt = bz >> 5;
    int m0 = mt * 128, n0 = nt * 128;
    int t = threadIdx.x, lane = t & 63;
    int w = t >> 6, wm = w >> 1, wn = w & 1;
    int lr = lane & 15, lc = lane >> 4;
    int sl = swz(lr);
    f32x4 acc[4][4] = {};
    for (int k0 = 0; k0 < NE; k0 += 32) {
        __syncthreads();
#pragma unroll
        for (int p = 0; p < 2; ++p) {
            int idx = p * 256 + t;
            int row = idx >> 2, c16 = (idx & 3) ^ swz(row);
            gl_lds16(lwT + (size_t)(m0 + row) * NE + k0 + c16 * 8, lA + idx * 8);
            gl_lds16(fwdT + (size_t)(n0 + row) * NE + k0 + c16 * 8, lB + idx * 8);
        }
        __syncthreads();
        bf16x8 af[4], bfr[4];
#pragma unroll
        for (int i = 0; i < 4; ++i)
            af[i] = *(const bf16x8*)&lA[(wm * 64 + i * 16 + lr) * 32 + ((lc ^ sl) << 3)];
#pragma unroll
        for (int j = 0; j < 4; ++j)
            bfr[j] = *(const bf16x8*)&lB[(wn * 64 + j * 16 + lr) * 32 + ((lc ^ sl) << 3)];
#pragma unroll
        for (int i = 0; i < 4; ++i)
#pragma unroll
            for (int j = 0; j < 4; ++j)
                acc[i][j] = __builtin_amdgcn_mfma_f32_16x16x32_bf16(af[i], bfr[j], acc[i][j], 0, 0, 0);
    }
#pragma unroll
    for (int i = 0; i < 4; ++i) {
        int mb = m0 + wm * 64 + i * 16 + lc * 4;
#pragma unroll
        for (int j = 0; j < 4; ++j) {
            int n = n0 + wn * 64 + j * 16 + lr;
            ushort4 v;
            v.x = cvt_bf16(acc[i][j][0]);
            v.y = cvt_bf16(acc[i][j][1]);
            v.z = cvt_bf16(acc[i][j][2]);
            v.w = cvt_bf16(acc[i][j][3]);
            *(ushort4*)&TMT[(size_t)n * NK + mb] = v;
        }
    }
}

// attr[b,a,j] = img[b]@TM_a[0:512] + edge[b,a]@TM_a[512:1024] + bvec_a[j]
// R7 winner verbatim: 512 thr / 8 waves, 128x256 tile, BK=32 dbuf, cf_pos,
// a=XCD, fused edge f32 (T14). attr via nontemporal store (not re-read).
template<bool WB>
__global__ __launch_bounds__(512) void k_mm4(const uint16_t* __restrict__ imgb,
                                             const float* __restrict__ edge,
                                             const uint16_t* __restrict__ TMT,
                                             const float* __restrict__ bvec,
                                             float* __restrict__ attr,
                                             uint16_t* __restrict__ attrb) {
    __shared__ alignas(16) uint16_t lA[2][128 * 32];   // 2 x 8 KB
    __shared__ alignas(16) uint16_t lB[2][256 * 32];   // 2 x 16 KB
    int o = blockIdx.x;             // 2048 = 8 xcd * (2 jt * 128 mt)
    int a = o & 7, idx = o >> 3;
    int jt = idx & 1, mt = idx >> 1;
    int m0 = mt * 128, jb = jt * 256;
    int t = threadIdx.x, lane = t & 63;
    int w = t >> 6, wm = w >> 2, wn = w & 3;
    int lr = lane & 15, lc = lane >> 4;
    int rpA = t >> 3, qA = (t & 7) ^ (rpA & 7);
    int srA = (rpA << 1) | (qA >> 2), scA = (qA & 3) << 3;
    int srB[2], scB[2];
#pragma unroll
    for (int p = 0; p < 2; ++p) {
        int u = t + p * 512;
        int rp = u >> 3, q = (u & 7) ^ (rp & 7);
        srB[p] = (rp << 1) | (q >> 2);
        scB[p] = (q & 3) << 3;
    }
    int er = t >> 2, ec = t & 3;
    int epos = cf_pos(er, ec) * 8;
    int aoff[4], boff[4];
#pragma unroll
    for (int i = 0; i < 4; ++i) {
        aoff[i] = cf_pos(wm * 64 + i * 16 + lr, lc) * 8;
        boff[i] = cf_pos(wn * 64 + i * 16 + lr, lc) * 8;
    }
    auto stage_img = [&](int buf, int s) {
        gl_lds16(imgb + (size_t)(m0 + srA) * NE + s * 32 + scA, &lA[buf][t * 8]);
    };
    auto stage_tmt = [&](int buf, int s) {
#pragma unroll
        for (int p = 0; p < 2; ++p)
            gl_lds16(TMT + (size_t)(a * NE + jb + srB[p]) * NK + s * 32 + scB[p],
                     &lB[buf][(t + p * 512) * 8]);
    };
    f32x4 acc[4][4] = {};
    stage_img(0, 0);
    stage_tmt(0, 0);
    for (int s = 0; s < 32; ++s) {
        int cur = s & 1, nb = cur ^ 1;
        __syncthreads();
        float4 e0, e1;
        bool eN = (s < 31) && (s + 1 >= 16);
        if (s < 31) {
            if (s + 1 < 16) {
                stage_img(nb, s + 1);
            } else {
                int kk = (s + 1 - 16) * 32;
                const float* sp = edge + ((size_t)(m0 + er) * NA + a) * NE + kk + ec * 8;
                e0 = ((const float4*)sp)[0];
                e1 = ((const float4*)sp)[1];
            }
            stage_tmt(nb, s + 1);
        }
        bf16x8 af[4], bfr[4];
#pragma unroll
        for (int i = 0; i < 4; ++i) af[i] = *(const bf16x8*)&lA[cur][aoff[i]];
#pragma unroll
        for (int j = 0; j < 4; ++j) bfr[j] = *(const bf16x8*)&lB[cur][boff[j]];
#pragma unroll
        for (int i = 0; i < 4; ++i)
#pragma unroll
            for (int j = 0; j < 4; ++j)
                acc[i][j] = __builtin_amdgcn_mfma_f32_16x16x32_bf16(af[i], bfr[j], acc[i][j], 0, 0, 0);
        if (eN) {
            u16x8 ov = {cvt_bf16(e0.x), cvt_bf16(e0.y), cvt_bf16(e0.z), cvt_bf16(e0.w),
                        cvt_bf16(e1.x), cvt_bf16(e1.y), cvt_bf16(e1.z), cvt_bf16(e1.w)};
            *(u16x8*)&lA[nb][epos] = ov;
        }
    }
#pragma unroll
    for (int j = 0; j < 4; ++j) {
        float bv = bvec[a * NE + jb + wn * 64 + j * 16 + lr];
#pragma unroll
        for (int i = 0; i < 4; ++i)
#pragma unroll
            for (int r = 0; r < 4; ++r)
                acc[i][j][r] += bv;
    }
#pragma unroll
    for (int i = 0; i < 4; ++i) {
#pragma unroll
        for (int r = 0; r < 4; ++r) {
            int bm = m0 + wm * 64 + i * 16 + lc * 4 + r;
            float* orow = attr + ((size_t)bm * NA + a) * NE + jb;
#pragma unroll
            for (int j = 0; j < 4; ++j)
                __builtin_nontemporal_store(acc[i][j][r], &orow[wn * 64 + j * 16 + lr]);
            if (WB) {
                uint16_t* brw = attrb + ((size_t)bm * NA + a) * NE + jb;
#pragma unroll
                for (int j = 0; j < 4; ++j)
                    brw[wn * 64 + j * 16 + lr] = cvt_bf16(acc[i][j][r]);
            }
        }
    }
}

// ind[b,j] += sum_{a in half} sw[a]*relu(attrb[b,a,:]@bwd_a[:,j])
// R7 winner verbatim: 256 thr, 128x128, BK=32 dbuf, cf_pos, (jt,ah)=XCD, a-split-2.
template<bool AB>
__global__ __launch_bounds__(256) void k_ind4(const float* __restrict__ attrf,
                                              const uint16_t* __restrict__ attrb,
                                              const uint16_t* __restrict__ bwdT,
                                              const float* __restrict__ sw,
                                              float* __restrict__ ind) {
    __shared__ alignas(16) uint16_t lA[2][128 * 32];
    __shared__ alignas(16) uint16_t lB[2][128 * 32];
    int o = blockIdx.x;            // 1024 = 8 xcd * 128 mt
    int xcd = o & 7, mt = o >> 3;
    int jt = xcd >> 1, ah = xcd & 1;
    int m0 = mt * 128, jb = jt * 128, a0 = ah * 4;
    int t = threadIdx.x, lane = t & 63;
    int w = t >> 6, wm = w >> 1, wn = w & 1;
    int lr = lane & 15, lc = lane >> 4;
    int srow[2], sc8[2];
#pragma unroll
    for (int p = 0; p < 2; ++p) {
        int u = p * 256 + t;
        int rp = u >> 3, q = (u & 7) ^ (rp & 7);
        srow[p] = (rp << 1) | (q >> 2);
        sc8[p] = (q & 3) << 3;
    }
    int erow[2], ec[2], epos[2];
#pragma unroll
    for (int p = 0; p < 2; ++p) {
        int u = p * 256 + t;
        erow[p] = u >> 2; ec[p] = u & 3;
        epos[p] = cf_pos(erow[p], ec[p]) * 8;
    }
    int aoff[4], boff[4];
#pragma unroll
    for (int i = 0; i < 4; ++i) {
        aoff[i] = cf_pos(wm * 64 + i * 16 + lr, lc) * 8;
        boff[i] = cf_pos(wn * 64 + i * 16 + lr, lc) * 8;
    }
    auto stage = [&](int buf, int s) {
        int aa = a0 + (s >> 4), kk = (s & 15) * 32;
        if (AB) {
#pragma unroll
            for (int p = 0; p < 2; ++p)
                gl_lds16(attrb + ((size_t)(m0 + srow[p]) * NA + aa) * NE + kk + sc8[p],
                         &lA[buf][(p * 256 + t) * 8]);
        } else {
#pragma unroll
            for (int p = 0; p < 2; ++p) {
                const float* sp = attrf + ((size_t)(m0 + erow[p]) * NA + aa) * NE + kk + ec[p] * 8;
                float4 v0 = ((const float4*)sp)[0];
                float4 v1 = ((const float4*)sp)[1];
                u16x8 ov = {cvt_bf16(v0.x), cvt_bf16(v0.y), cvt_bf16(v0.z), cvt_bf16(v0.w),
                            cvt_bf16(v1.x), cvt_bf16(v1.y), cvt_bf16(v1.z), cvt_bf16(v1.w)};
                *(u16x8*)&lA[buf][epos[p]] = ov;
            }
        }
#pragma unroll
        for (int p = 0; p < 2; ++p)
            gl_lds16(bwdT + (size_t)(aa * NE + jb + srow[p]) * NE + kk + sc8[p],
                     &lB[buf][(p * 256 + t) * 8]);
    };
    f32x4 res[4][4] = {};
    f32x4 acc[4][4] = {};
    stage(0, 0);
    for (int s = 0; s < 64; ++s) {
        int cur = s & 1;
        __syncthreads();
        if (s < 63) stage(cur ^ 1, s + 1);
        bf16x8 af[4], bfr[4];
#pragma unroll
        for (int i = 0; i < 4; ++i) af[i] = *(const bf16x8*)&lA[cur][aoff[i]];
#pragma unroll
        for (int j = 0; j < 4; ++j) bfr[j] = *(const bf16x8*)&lB[cur][boff[j]];
#pragma unroll
        for (int i = 0; i < 4; ++i)
#pragma unroll
            for (int j = 0; j < 4; ++j)
                acc[i][j] = __builtin_amdgcn_mfma_f32_16x16x32_bf16(af[i], bfr[j], acc[i][j], 0, 0, 0);
        if ((s & 15) == 15) {
            float wa = sw[a0 + (s >> 4)];
#pragma unroll
            for (int i = 0; i < 4; ++i)
#pragma unroll
                for (int j = 0; j < 4; ++j) {
#pragma unroll
                    for (int r = 0; r < 4; ++r)
                        res[i][j][r] += wa * fmaxf(acc[i][j][r], 0.f);
                    acc[i][j] = (f32x4){0.f, 0.f, 0.f, 0.f};
                }
        }
    }
#pragma unroll
    for (int i = 0; i < 4; ++i) {
#pragma unroll
        for (int r = 0; r < 4; ++r) {
            int bm = m0 + wm * 64 + i * 16 + lc * 4 + r;
            float* orow = ind + (size_t)bm * NE + jb;
#pragma unroll
            for (int j = 0; j < 4; ++j)
                atomicAdd(&orow[wn * 64 + j * 16 + lr], res[i][j][r]);
        }
    }
}

extern "C" void kernel_launch(void* const* d_in, const int* in_sizes, int n_in,
                              void* d_out, int out_size, void* d_ws, size_t ws_size,
                              hipStream_t stream) {
    (void)in_sizes; (void)n_in; (void)out_size;
    const float* img  = (const float*)d_in[0];
    const float* edge = (const float*)d_in[1];
    const float* lw   = (const float*)d_in[2];
    const float* lb   = (const float*)d_in[3];
    const float* fwd  = (const float*)d_in[4];
    const float* bwd  = (const float*)d_in[5];
    const float* sw   = (const float*)d_in[6];
    float* attr = (float*)d_out;
    float* ind  = attr + (size_t)NB * NA * NE;

    char* ws = (char*)d_ws;
    size_t off = 0;
    auto alloc = [&](size_t bytes) { void* p = ws + off; off += bytes; return p; };
    uint16_t* lwT  = (uint16_t*)alloc((size_t)NK * NE * 2);       // 1 MB
    uint16_t* fwdT = (uint16_t*)alloc((size_t)NA * NE * NE * 2);  // 4 MB
    uint16_t* bwdT = (uint16_t*)alloc((size_t)NA * NE * NE * 2);  // 4 MB
    uint16_t* TMT  = (uint16_t*)alloc((size_t)NN * NK * 2);       // 8 MB
    uint16_t* imgb = (uint16_t*)alloc((size_t)NB * NE * 2);       // 16 MB
    float*    bvec = (float*)alloc((size_t)NN * 4);               // 16 KB

    const size_t BIGB = (size_t)NB * NA * NE * 2;  // 128 MB
    bool has_attrb = ws_size >= off + BIGB;
    uint16_t* attrb = has_attrb ? (uint16_t*)alloc(BIGB) : (uint16_t*)0;

    hipMemsetAsync(bvec, 0, (size_t)NN * 4, stream);
    hipMemsetAsync(ind, 0, (size_t)NB * NE * 4, stream);

    k_pre<<<12928, 256, 0, stream>>>(lw, fwd, bwd, img, lb, lwT, fwdT, bwdT, imgb, bvec);
    k_prep<<<(NK / 128) * (NN / 128), 256, 0, stream>>>(lwT, fwdT, TMT);

    int mm_grid = 8 * 2 * (NB / 128);            // 2048 blocks of 512 threads
    int ind_grid = (NB / 128) * (NE / 128) * 2;  // 1024 blocks of 256 threads

    if (has_attrb) {
        k_mm4<true><<<mm_grid, 512, 0, stream>>>(imgb, edge, TMT, bvec, attr, attrb);
        k_ind4<true><<<ind_grid, 256, 0, stream>>>(attr, attrb, bwdT, sw, ind);
    } else {
        k_mm4<false><<<mm_grid, 512, 0, stream>>>(imgb, edge, TMT, bvec, attr, attrb);
        k_ind4<false><<<ind_grid, 256, 0, stream>>>(attr, attrb, bwdT, sw, ind);
    }
}